// Round 14
// baseline (433.252 us; speedup 1.0000x reference)
//
#include <hip/hip_runtime.h>
#include <hip/hip_bf16.h>
#include <math.h>

#define N_NODES 50000
#define N_EDGES 800000
#define BN_EPS  1e-5f
#define SCAN_NB 49     // ceil(50000/1024)
#define AGG_NB  2048   // agg grid blocks

// ---- workspace layout (float-element offsets) ----
#define OFS_RELW   0
#define OFS_KH     20480                         // 50000*128 ushort = 3.2M floats
#define OFS_Q      (OFS_KH + 5000000)
#define OFS_VH     (OFS_Q + 5000000)             // 50000*128 ushort
#define OFS_ATTP   (OFS_VH + 5000000)
#define OFS_BNPART (OFS_ATTP + 800000)           // 200 * AGG_NB
#define OFS_BNSC   (OFS_BNPART + 200 * AGG_NB)
#define OFS_BNSH   (OFS_BNSC + 128)
// int region
#define OFS_CNT    (OFS_BNSH + 128)
#define OFS_PART   (OFS_CNT + 50176)
#define OFS_BSUM   (OFS_PART + 50176)
#define OFS_OFFS   (OFS_BSUM + 64)
#define OFS_CURS   (OFS_OFFS + 50176)
#define OFS_PERM   (OFS_CURS + 50176)
#define OFS_PSRC   (OFS_PERM + 800000)
#define OFS_WT     (OFS_PSRC + 800000)           // 4 * 100 * 104 transposed W
#define WS_ELEMS   (OFS_WT + 41600)

__device__ __forceinline__ unsigned short f2bf(float f) {   // RNE float->bf16
    unsigned u = __float_as_uint(f);
    return (unsigned short)((u + 0x7FFFu + ((u >> 16) & 1u)) >> 16);
}
__device__ __forceinline__ float bf2f(unsigned short h) {
    return __uint_as_float((unsigned)h << 16);
}

// rel_w[r][c] = sum_b w_comp[r][b] * relation_att[b][c]
__global__ __launch_bounds__(256) void relw_kernel(
    const float* __restrict__ wcomp, const float* __restrict__ ratt,
    float* __restrict__ relw)
{
    int o = blockIdx.x * 256 + threadIdx.x;
    if (o >= 200 * 100) return;
    int r = o / 100, c = o % 100;
    float acc = 0.f;
    #pragma unroll 10
    for (int b = 0; b < 50; ++b) acc += wcomp[r * 50 + b] * ratt[b * 100 + c];
    relw[o] = acc;
}

// pre-transpose W to d-major, rows padded to 104: Wt[m][d][c] = Wm[c][d]
__global__ __launch_bounds__(256) void wt_kernel(
    const float* __restrict__ Wk, const float* __restrict__ Wq,
    const float* __restrict__ Wv, const float* __restrict__ Ws,
    float* __restrict__ Wt)
{
    int o = blockIdx.x * 256 + threadIdx.x;
    if (o >= 4 * 100 * 104) return;
    int m = o / 10400, rem = o % 10400, d = rem / 104, c = rem % 104;
    const float* W = (m == 0) ? Wk : (m == 1) ? Wq : (m == 2) ? Wv : Ws;
    Wt[o] = (c < 100) ? W[c * 100 + d] : 0.f;
}

// fused projections: 8x8 register tile, both operands read as b128.
// 128 threads = 2 waves; node tile 64 (split {4ng,32+4ng}), col tile 104
// (split {4cg,52+4cg}) -> each b128's 8 lane-addresses hit 8 distinct bank
// quads = conflict-free. Xt staging writes XOR-swizzled (col = n^((d4&7)<<2))
// to break the 12-way transpose-write conflict; reads apply the same key.
// Per d-step/wave: 4 b128 (48 LDS-cy) per 128 VALU-cy -> ~2x less LDS
// pressure than the R12 4x4 tile. m=0,2 outputs bf16 (128-elem rows).
__global__ __launch_bounds__(128) void proj_kernel(
    const float* __restrict__ X, const float* __restrict__ Wt,
    const float* __restrict__ bk, const float* __restrict__ bq,
    const float* __restrict__ bv, const float* __restrict__ bs,
    unsigned short* __restrict__ kh, float* __restrict__ qo,
    unsigned short* __restrict__ vh, float* __restrict__ so)
{
    __shared__ float Xt[100][68];    // 27.2 KB, swizzled transposed X
    __shared__ float Wl[100][104];   // 41.6 KB, d-major W (68.8 KB total)
    const int tid = threadIdx.x;
    const int nb  = blockIdx.x * 64;
    const int m   = blockIdx.y;

    const float* bp = (m == 0) ? bk : (m == 1) ? bq : (m == 2) ? bv : bs;

    // stage W: 100 rows x 26 float4, coalesced from pre-transposed global
    for (int idx = tid; idx < 2600; idx += 128) {
        int r = idx / 26, c4 = idx % 26;
        float4 w = ((const float4*)(Wt + m * 10400 + r * 104))[c4];
        *(float4*)&Wl[r][c4 * 4] = w;
    }
    // stage X transposed + XOR-swizzled columns
    for (int idx = tid; idx < 1600; idx += 128) {
        int n = idx / 25, d4 = idx % 25;
        int node = nb + n;
        float4 x = (node < N_NODES)
                   ? ((const float4*)(X + (size_t)node * 100))[d4]
                   : make_float4(0.f, 0.f, 0.f, 0.f);
        const int col = n ^ ((d4 & 7) << 2);
        Xt[4 * d4 + 0][col] = x.x;
        Xt[4 * d4 + 1][col] = x.y;
        Xt[4 * d4 + 2][col] = x.z;
        Xt[4 * d4 + 3][col] = x.w;
    }
    __syncthreads();

    const int ng = tid & 7;          // node group: nodes {4ng..+3, 32+4ng..+3}
    const int cg = tid >> 3;         // col group 0..15 (13 active)
    const bool act = (cg < 13);
    const int cgs = act ? cg : 12;

    float acc[8][8];
    #pragma unroll
    for (int i = 0; i < 8; ++i)
        #pragma unroll
        for (int j = 0; j < 8; ++j) acc[i][j] = 0.f;

    #pragma unroll 2
    for (int d = 0; d < 100; ++d) {
        const int key = ((d >> 2) & 7) << 2;
        const int c0  = (4 * ng) ^ key;
        const float4 xa = *(const float4*)&Xt[d][c0];        // nodes 4ng..+3
        const float4 xb = *(const float4*)&Xt[d][c0 + 32];   // nodes 32+4ng..+3
        const float4 wa = *(const float4*)&Wl[d][4 * cgs];
        const float4 wb = *(const float4*)&Wl[d][52 + 4 * cgs];
        const float xs[8] = {xa.x, xa.y, xa.z, xa.w, xb.x, xb.y, xb.z, xb.w};
        const float wv[8] = {wa.x, wa.y, wa.z, wa.w, wb.x, wb.y, wb.z, wb.w};
        #pragma unroll
        for (int i = 0; i < 8; ++i)
            #pragma unroll
            for (int j = 0; j < 8; ++j)
                acc[i][j] += xs[i] * wv[j];
    }

    if (act) {
        const bool act2 = (52 + 4 * cg < 100);       // cg < 12
        const float4 ba = *(const float4*)(bp + 4 * cg);
        const float4 bb = act2 ? *(const float4*)(bp + 52 + 4 * cg)
                               : make_float4(0.f, 0.f, 0.f, 0.f);
        #pragma unroll
        for (int i = 0; i < 8; ++i) {
            const int node = nb + ((i < 4) ? (4 * ng + i) : (32 + 4 * ng + i - 4));
            if (node >= N_NODES) continue;
            const float r0 = acc[i][0] + ba.x, r1 = acc[i][1] + ba.y;
            const float r2 = acc[i][2] + ba.z, r3 = acc[i][3] + ba.w;
            const float r4 = acc[i][4] + bb.x, r5 = acc[i][5] + bb.y;
            const float r6 = acc[i][6] + bb.z, r7 = acc[i][7] + bb.w;
            if (m == 0 || m == 2) {
                unsigned short* oph = (m == 0) ? kh : vh;
                ushort4 h0 = make_ushort4(f2bf(r0), f2bf(r1), f2bf(r2), f2bf(r3));
                *(ushort4*)(oph + (size_t)node * 128 + 4 * cg) = h0;
                if (act2) {
                    ushort4 h1 = make_ushort4(f2bf(r4), f2bf(r5), f2bf(r6), f2bf(r7));
                    *(ushort4*)(oph + (size_t)node * 128 + 52 + 4 * cg) = h1;
                }
            } else {
                float* opf = (m == 1) ? qo : so;
                *(float4*)(opf + (size_t)node * 100 + 4 * cg)
                    = make_float4(r0, r1, r2, r3);
                if (act2)
                    *(float4*)(opf + (size_t)node * 100 + 52 + 4 * cg)
                        = make_float4(r4, r5, r6, r7);
            }
        }
    }
}

__global__ __launch_bounds__(256) void hist_kernel(
    const int* __restrict__ dst, int* __restrict__ cnt)
{
    int e = blockIdx.x * 256 + threadIdx.x;
    if (e < N_EDGES) atomicAdd(&cnt[dst[e]], 1);
}

__global__ __launch_bounds__(1024) void scanA_kernel(
    const int* __restrict__ cnt, int* __restrict__ partial, int* __restrict__ bsum)
{
    __shared__ int buf[1024];
    int tid = threadIdx.x;
    int i = blockIdx.x * 1024 + tid;
    int val = (i < N_NODES) ? cnt[i] : 0;
    buf[tid] = val;
    __syncthreads();
    for (int off = 1; off < 1024; off <<= 1) {
        int t = (tid >= off) ? buf[tid - off] : 0;
        __syncthreads();
        buf[tid] += t;
        __syncthreads();
    }
    int incl = buf[tid];
    if (i < N_NODES) partial[i] = incl - val;
    if (tid == 1023) bsum[blockIdx.x] = incl;
}

__global__ __launch_bounds__(1024) void scanB_kernel(
    const int* __restrict__ partial, const int* __restrict__ bsum,
    int* __restrict__ offs)
{
    __shared__ int bs[64];
    int tid = threadIdx.x;
    if (tid < SCAN_NB) bs[tid] = bsum[tid];
    __syncthreads();
    if (tid == 0) {
        int run = 0;
        for (int b = 0; b < SCAN_NB; ++b) { int t = bs[b]; bs[b] = run; run += t; }
    }
    __syncthreads();
    for (int i = tid; i < N_NODES; i += 1024) offs[i] = partial[i] + bs[i >> 10];
    if (tid == 0) offs[N_NODES] = N_EDGES;
}

__global__ __launch_bounds__(256) void scatter_kernel(
    const int* __restrict__ src, const int* __restrict__ dst,
    const int* __restrict__ offs, int* __restrict__ cursor,
    int* __restrict__ perm, int* __restrict__ psrc)
{
    int e = blockIdx.x * 256 + threadIdx.x;
    if (e >= N_EDGES) return;
    int d = dst[e];
    int p = atomicAdd(&cursor[d], 1);
    int pos = offs[d] + p;
    perm[pos] = e;
    psrc[pos] = src[e];
}

// attention logits in CSR position order: 32 lanes/edge; k gathered as bf16
__global__ __launch_bounds__(256) void attp_kernel(
    const unsigned short* __restrict__ kh, const float* __restrict__ q,
    const float* __restrict__ relw, const int* __restrict__ perm,
    const int* __restrict__ src, const int* __restrict__ dst,
    const int* __restrict__ etype, float* __restrict__ attp)
{
    const int lane = threadIdx.x & 31;
    const int i = blockIdx.x * 8 + (threadIdx.x >> 5);
    if (i >= N_EDGES) return;
    const int e = perm[i];
    const int s_ = src[e], d_ = dst[e], t_ = etype[e];
    float acc = 0.f;
    if (lane < 25) {
        const ushort4 kt = ((const ushort4*)(kh + (size_t)s_ * 128))[lane];
        const float4 qv = ((const float4*)(q + (size_t)d_ * 100))[lane];
        const float4 wv = ((const float4*)(relw + t_ * 100))[lane];
        acc = bf2f(kt.x) * wv.x * qv.x + bf2f(kt.y) * wv.y * qv.y
            + bf2f(kt.z) * wv.z * qv.z + bf2f(kt.w) * wv.w * qv.w;
    }
    #pragma unroll
    for (int off = 16; off > 0; off >>= 1) acc += __shfl_xor(acc, off, 32);
    if (lane == 0) attp[i] = acc;
}

// one wave per node: softmax + weighted-V aggregate (v bf16) + gated combine
// + BN partials
__global__ __launch_bounds__(256) void agg_kernel(
    const int* __restrict__ offs, const int* __restrict__ psrc,
    const float* __restrict__ attp, const unsigned short* __restrict__ vh,
    const float* __restrict__ alpha, float* __restrict__ out,
    float* __restrict__ bnpart)
{
    __shared__ float ls[100], lq[100];
    const int tid = threadIdx.x;
    if (tid < 100) { ls[tid] = 0.f; lq[tid] = 0.f; }
    __syncthreads();
    const int lane = tid & 63;
    const int gwave = blockIdx.x * 4 + (tid >> 6);
    const int nwaves = AGG_NB * 4;
    const float a = 1.f / (1.f + __expf(-alpha[0]));
    const float b = 1.f - a;
    const int cl = lane;
    const bool act = (cl < 50);
    float sx = 0.f, sy = 0.f, qx = 0.f, qy = 0.f;

    for (int n = gwave; n < N_NODES; n += nwaves) {
        const int beg = offs[n], end = offs[n + 1];
        float m = -INFINITY;
        for (int i = beg + lane; i < end; i += 64) m = fmaxf(m, attp[i]);
        #pragma unroll
        for (int off = 32; off > 0; off >>= 1) m = fmaxf(m, __shfl_xor(m, off, 64));
        float ax = 0.f, ay = 0.f, wsum = 0.f;
        int i = beg;
        for (; i + 4 <= end; i += 4) {
            const int s0 = psrc[i], s1 = psrc[i + 1], s2 = psrc[i + 2], s3 = psrc[i + 3];
            const float w0 = __expf(attp[i] - m),     w1 = __expf(attp[i + 1] - m);
            const float w2 = __expf(attp[i + 2] - m), w3 = __expf(attp[i + 3] - m);
            wsum += w0 + w1 + w2 + w3;
            if (act) {
                const unsigned h0 = ((const unsigned*)(vh + (size_t)s0 * 128))[cl];
                const unsigned h1 = ((const unsigned*)(vh + (size_t)s1 * 128))[cl];
                const unsigned h2 = ((const unsigned*)(vh + (size_t)s2 * 128))[cl];
                const unsigned h3 = ((const unsigned*)(vh + (size_t)s3 * 128))[cl];
                ax += w0 * bf2f((unsigned short)(h0 & 0xFFFFu))
                    + w1 * bf2f((unsigned short)(h1 & 0xFFFFu))
                    + w2 * bf2f((unsigned short)(h2 & 0xFFFFu))
                    + w3 * bf2f((unsigned short)(h3 & 0xFFFFu));
                ay += w0 * bf2f((unsigned short)(h0 >> 16))
                    + w1 * bf2f((unsigned short)(h1 >> 16))
                    + w2 * bf2f((unsigned short)(h2 >> 16))
                    + w3 * bf2f((unsigned short)(h3 >> 16));
            }
        }
        for (; i < end; ++i) {
            const int s0 = psrc[i];
            const float w0 = __expf(attp[i] - m);
            wsum += w0;
            if (act) {
                const unsigned h0 = ((const unsigned*)(vh + (size_t)s0 * 128))[cl];
                ax += w0 * bf2f((unsigned short)(h0 & 0xFFFFu));
                ay += w0 * bf2f((unsigned short)(h0 >> 16));
            }
        }
        const float inv = (wsum > 0.f) ? 1.f / wsum : 0.f;
        if (act) {
            float2* po = (float2*)(out + (size_t)n * 100);
            float2 cur = po[cl];
            float v0 = a * cur.x + b * ax * inv;
            float v1 = a * cur.y + b * ay * inv;
            po[cl] = make_float2(v0, v1);
            sx += v0; qx += v0 * v0;
            sy += v1; qy += v1 * v1;
        }
    }
    if (act) {
        atomicAdd(&ls[2 * cl], sx);     atomicAdd(&ls[2 * cl + 1], sy);
        atomicAdd(&lq[2 * cl], qx);     atomicAdd(&lq[2 * cl + 1], qy);
    }
    __syncthreads();
    if (tid < 100) {
        bnpart[(size_t)tid * AGG_NB + blockIdx.x]         = ls[tid];
        bnpart[(size_t)(tid + 100) * AGG_NB + blockIdx.x] = lq[tid];
    }
}

__global__ __launch_bounds__(256) void bnfin_kernel(
    const float* __restrict__ bnpart,
    const float* __restrict__ gamma, const float* __restrict__ beta,
    float* __restrict__ bnsc, float* __restrict__ bnsh)
{
    const int c = blockIdx.x * 4 + (threadIdx.x >> 6);
    const int lane = threadIdx.x & 63;
    if (c >= 100) return;
    float s = 0.f, q = 0.f;
    for (int b2 = lane; b2 < AGG_NB; b2 += 64) {
        s += bnpart[(size_t)c * AGG_NB + b2];
        q += bnpart[(size_t)(c + 100) * AGG_NB + b2];
    }
    #pragma unroll
    for (int off = 32; off > 0; off >>= 1) {
        s += __shfl_xor(s, off, 64);
        q += __shfl_xor(q, off, 64);
    }
    if (lane == 0) {
        const float inv_n = 1.f / (float)N_NODES;
        float mean = s * inv_n;
        float var = q * inv_n - mean * mean;
        float sc = gamma[c] * rsqrtf(var + BN_EPS);
        bnsc[c] = sc;
        bnsh[c] = beta[c] - mean * sc;
    }
}

__global__ __launch_bounds__(256) void apply_kernel(
    float* __restrict__ out, const float* __restrict__ bnsc,
    const float* __restrict__ bnsh)
{
    const int total4 = N_NODES * 25;
    for (int idx = blockIdx.x * 256 + threadIdx.x; idx < total4; idx += gridDim.x * 256) {
        float4* p = ((float4*)out) + idx;
        const int c = (idx % 25) * 4;
        float4 t = *p;
        t.x = tanhf(t.x * bnsc[c]     + bnsh[c]);
        t.y = tanhf(t.y * bnsc[c + 1] + bnsh[c + 1]);
        t.z = tanhf(t.z * bnsc[c + 2] + bnsh[c + 2]);
        t.w = tanhf(t.w * bnsc[c + 3] + bnsh[c + 3]);
        *p = t;
    }
}

__global__ __launch_bounds__(256) void rout_kernel(
    const float* __restrict__ rf, const float* __restrict__ Wr,
    const float* __restrict__ br, float* __restrict__ out)
{
    int o = blockIdx.x * 256 + threadIdx.x;
    if (o >= 200 * 100) return;
    int r = o / 100, c = o % 100;
    float acc = br[c];
    #pragma unroll 10
    for (int d = 0; d < 100; ++d) acc += rf[r * 100 + d] * Wr[c * 100 + d];
    out[N_NODES * 100 + o] = acc;
}

extern "C" void kernel_launch(void* const* d_in, const int* in_sizes, int n_in,
                              void* d_out, int out_size, void* d_ws, size_t ws_size,
                              hipStream_t stream) {
    const float* X     = (const float*)d_in[0];
    const float* rfeat = (const float*)d_in[1];
    const int*   src   = (const int*)d_in[2];
    const int*   dst   = (const int*)d_in[3];
    const int*   ety   = (const int*)d_in[4];
    const float* Wsw   = (const float*)d_in[6];
    const float* Wsb   = (const float*)d_in[7];
    const float* Wkw   = (const float*)d_in[8];
    const float* Wkb   = (const float*)d_in[9];
    const float* Wqw   = (const float*)d_in[10];
    const float* Wqb   = (const float*)d_in[11];
    const float* Wvw   = (const float*)d_in[12];
    const float* Wvb   = (const float*)d_in[13];
    const float* Wrw   = (const float*)d_in[14];
    const float* Wrb   = (const float*)d_in[15];
    const float* ratt  = (const float*)d_in[16];
    const float* wcomp = (const float*)d_in[17];
    const float* alpha = (const float*)d_in[18];
    const float* gamma = (const float*)d_in[20];
    const float* beta  = (const float*)d_in[21];

    float* out = (float*)d_out;
    float* ws  = (float*)d_ws;
    if (ws_size < (size_t)WS_ELEMS * sizeof(float)) return;

    float* relw        = ws + OFS_RELW;
    unsigned short* kh = (unsigned short*)(ws + OFS_KH);
    float* q           = ws + OFS_Q;
    unsigned short* vh = (unsigned short*)(ws + OFS_VH);
    float* attp        = ws + OFS_ATTP;
    float* bnpart      = ws + OFS_BNPART;
    float* bnsc        = ws + OFS_BNSC;
    float* bnsh        = ws + OFS_BNSH;
    float* Wt          = ws + OFS_WT;
    int* cnt           = (int*)(ws + OFS_CNT);
    int* partial       = (int*)(ws + OFS_PART);
    int* bsum          = (int*)(ws + OFS_BSUM);
    int* offs          = (int*)(ws + OFS_OFFS);
    int* cursor        = (int*)(ws + OFS_CURS);
    int* perm          = (int*)(ws + OFS_PERM);
    int* psrc          = (int*)(ws + OFS_PSRC);

    hipMemsetAsync(cnt, 0, 50000 * sizeof(int), stream);
    hipMemsetAsync(cursor, 0, 50000 * sizeof(int), stream);

    relw_kernel<<<(20000 + 255) / 256, 256, 0, stream>>>(wcomp, ratt, relw);
    wt_kernel<<<(41600 + 255) / 256, 256, 0, stream>>>(Wkw, Wqw, Wvw, Wsw, Wt);
    proj_kernel<<<dim3((N_NODES + 63) / 64, 4), 128, 0, stream>>>(
        X, Wt, Wkb, Wqb, Wvb, Wsb, kh, q, vh, out);

    hist_kernel<<<(N_EDGES + 255) / 256, 256, 0, stream>>>(dst, cnt);
    scanA_kernel<<<SCAN_NB, 1024, 0, stream>>>(cnt, partial, bsum);
    scanB_kernel<<<1, 1024, 0, stream>>>(partial, bsum, offs);
    scatter_kernel<<<(N_EDGES + 255) / 256, 256, 0, stream>>>(src, dst, offs, cursor, perm, psrc);

    attp_kernel<<<(N_EDGES + 7) / 8, 256, 0, stream>>>(
        kh, q, relw, perm, src, dst, ety, attp);
    agg_kernel<<<AGG_NB, 256, 0, stream>>>(offs, psrc, attp, vh, alpha, out, bnpart);
    bnfin_kernel<<<25, 256, 0, stream>>>(bnpart, gamma, beta, bnsc, bnsh);
    apply_kernel<<<2048, 256, 0, stream>>>(out, bnsc, bnsh);
    rout_kernel<<<(20000 + 255) / 256, 256, 0, stream>>>(rfeat, Wrw, Wrb, out);
}

// Round 15
// 360.689 us; speedup vs baseline: 1.2012x; 1.2012x over previous
//
#include <hip/hip_runtime.h>
#include <hip/hip_bf16.h>
#include <math.h>

#define N_NODES 50000
#define N_EDGES 800000
#define BN_EPS  1e-5f
#define SCAN_NB 49     // ceil(50000/1024)
#define AGG_NB  2048   // agg grid blocks

// ---- workspace layout (float-element offsets) ----
#define OFS_RELW   0
#define OFS_KH     20480                         // 50000*128 ushort = 3.2M floats
#define OFS_Q      (OFS_KH + 5000000)
#define OFS_VH     (OFS_Q + 5000000)             // 50000*128 ushort
#define OFS_ATTP   (OFS_VH + 5000000)
#define OFS_BNPART (OFS_ATTP + 800000)           // 200 * AGG_NB
#define OFS_BNSC   (OFS_BNPART + 200 * AGG_NB)
#define OFS_BNSH   (OFS_BNSC + 128)
// int region
#define OFS_CNT    (OFS_BNSH + 128)
#define OFS_PART   (OFS_CNT + 50176)
#define OFS_BSUM   (OFS_PART + 50176)
#define OFS_OFFS   (OFS_BSUM + 64)
#define OFS_CURS   (OFS_OFFS + 50176)
#define OFS_PERM   (OFS_CURS + 50176)
#define OFS_PSRC   (OFS_PERM + 800000)
#define OFS_WT     (OFS_PSRC + 800000)           // 4 * 100 * 104 transposed W
#define WS_ELEMS   (OFS_WT + 41600)

__device__ __forceinline__ unsigned short f2bf(float f) {   // RNE float->bf16
    unsigned u = __float_as_uint(f);
    return (unsigned short)((u + 0x7FFFu + ((u >> 16) & 1u)) >> 16);
}
__device__ __forceinline__ float bf2f(unsigned short h) {
    return __uint_as_float((unsigned)h << 16);
}

// rel_w[r][c] = sum_b w_comp[r][b] * relation_att[b][c]
__global__ __launch_bounds__(256) void relw_kernel(
    const float* __restrict__ wcomp, const float* __restrict__ ratt,
    float* __restrict__ relw)
{
    int o = blockIdx.x * 256 + threadIdx.x;
    if (o >= 200 * 100) return;
    int r = o / 100, c = o % 100;
    float acc = 0.f;
    #pragma unroll 10
    for (int b = 0; b < 50; ++b) acc += wcomp[r * 50 + b] * ratt[b * 100 + c];
    relw[o] = acc;
}

// pre-transpose W to d-major, rows padded to 104: Wt[m][d][c] = Wm[c][d]
__global__ __launch_bounds__(256) void wt_kernel(
    const float* __restrict__ Wk, const float* __restrict__ Wq,
    const float* __restrict__ Wv, const float* __restrict__ Ws,
    float* __restrict__ Wt)
{
    int o = blockIdx.x * 256 + threadIdx.x;
    if (o >= 4 * 100 * 104) return;
    int m = o / 10400, rem = o % 10400, d = rem / 104, c = rem % 104;
    const float* W = (m == 0) ? Wk : (m == 1) ? Wq : (m == 2) ? Wv : Ws;
    Wt[o] = (c < 100) ? W[c * 100 + d] : 0.f;
}

// fused projections: R13 structure (512 thr, 4x4 tile, 2 blocks/CU,
// 16 waves/CU) with its two LDS defects fixed:
//  - W d-major in LDS -> wave reads 4 b128 chunks on 16 consecutive banks
//    (R13's row-major W b32 reads were a uniform 4-way bank conflict)
//  - Xt staging writes XOR-swizzled (col = n^((d4&7)<<2)); reads use the
//    same key (X b128 reads span all 32 banks 2-way = free)
// m=0 (k) and m=2 (v) written as bf16, rows padded to 128 elems.
__global__ __launch_bounds__(512) void proj_kernel(
    const float* __restrict__ X, const float* __restrict__ Wt,
    const float* __restrict__ bk, const float* __restrict__ bq,
    const float* __restrict__ bv, const float* __restrict__ bs,
    unsigned short* __restrict__ kh, float* __restrict__ qo,
    unsigned short* __restrict__ vh, float* __restrict__ so)
{
    __shared__ float Xt[100][68];    // swizzled transposed X: 27.2 KB
    __shared__ float Wl[100][104];   // d-major W:            41.6 KB (68.8 KB)
    const int tid = threadIdx.x;
    const int nb  = blockIdx.x * 64;
    const int m   = blockIdx.y;

    const float* bp = (m == 0) ? bk : (m == 1) ? bq : (m == 2) ? bv : bs;

    // stage W: coalesced from pre-transposed global, consecutive-bank writes
    for (int idx = tid; idx < 2600; idx += 512) {
        int r = idx / 26, c4 = idx % 26;
        float4 w = ((const float4*)(Wt + m * 10400 + r * 104))[c4];
        *(float4*)&Wl[r][c4 * 4] = w;
    }
    // stage X transposed + XOR-swizzled columns
    for (int idx = tid; idx < 1600; idx += 512) {
        int n = idx / 25, d4 = idx % 25;
        int node = nb + n;
        float4 x = (node < N_NODES)
                   ? ((const float4*)(X + (size_t)node * 100))[d4]
                   : make_float4(0.f, 0.f, 0.f, 0.f);
        const int col = n ^ ((d4 & 7) << 2);
        Xt[4 * d4 + 0][col] = x.x;
        Xt[4 * d4 + 1][col] = x.y;
        Xt[4 * d4 + 2][col] = x.z;
        Xt[4 * d4 + 3][col] = x.w;
    }
    __syncthreads();

    const int nt  = tid & 15;        // node group: nodes 4nt..4nt+3
    const int ct  = tid >> 4;        // col group 0..31 (25 active)
    const bool act = (ct < 25);
    const int cts  = act ? ct : 24;

    float acc[4][4];
    #pragma unroll
    for (int i = 0; i < 4; ++i)
        #pragma unroll
        for (int j = 0; j < 4; ++j) acc[i][j] = 0.f;

    #pragma unroll 4
    for (int d = 0; d < 100; ++d) {
        const int key = ((d >> 2) & 7) << 2;
        const float4 xv = *(const float4*)&Xt[d][(4 * nt) ^ key];
        const float4 wv = *(const float4*)&Wl[d][4 * cts];
        acc[0][0] += xv.x * wv.x; acc[0][1] += xv.x * wv.y;
        acc[0][2] += xv.x * wv.z; acc[0][3] += xv.x * wv.w;
        acc[1][0] += xv.y * wv.x; acc[1][1] += xv.y * wv.y;
        acc[1][2] += xv.y * wv.z; acc[1][3] += xv.y * wv.w;
        acc[2][0] += xv.z * wv.x; acc[2][1] += xv.z * wv.y;
        acc[2][2] += xv.z * wv.z; acc[2][3] += xv.z * wv.w;
        acc[3][0] += xv.w * wv.x; acc[3][1] += xv.w * wv.y;
        acc[3][2] += xv.w * wv.z; acc[3][3] += xv.w * wv.w;
    }

    if (act) {
        const float4 bb = *(const float4*)(bp + ct * 4);
        if (m == 0 || m == 2) {
            unsigned short* oph = (m == 0) ? kh : vh;
            #pragma unroll
            for (int i = 0; i < 4; ++i) {
                const int node = nb + nt * 4 + i;
                if (node < N_NODES) {
                    ushort4 hh;
                    hh.x = f2bf(acc[i][0] + bb.x);
                    hh.y = f2bf(acc[i][1] + bb.y);
                    hh.z = f2bf(acc[i][2] + bb.z);
                    hh.w = f2bf(acc[i][3] + bb.w);
                    *(ushort4*)(oph + (size_t)node * 128 + ct * 4) = hh;
                }
            }
        } else {
            float* opf = (m == 1) ? qo : so;
            #pragma unroll
            for (int i = 0; i < 4; ++i) {
                const int node = nb + nt * 4 + i;
                if (node < N_NODES) {
                    float4 r = make_float4(acc[i][0] + bb.x, acc[i][1] + bb.y,
                                           acc[i][2] + bb.z, acc[i][3] + bb.w);
                    *(float4*)(opf + (size_t)node * 100 + ct * 4) = r;
                }
            }
        }
    }
}

__global__ __launch_bounds__(256) void hist_kernel(
    const int* __restrict__ dst, int* __restrict__ cnt)
{
    int e = blockIdx.x * 256 + threadIdx.x;
    if (e < N_EDGES) atomicAdd(&cnt[dst[e]], 1);
}

__global__ __launch_bounds__(1024) void scanA_kernel(
    const int* __restrict__ cnt, int* __restrict__ partial, int* __restrict__ bsum)
{
    __shared__ int buf[1024];
    int tid = threadIdx.x;
    int i = blockIdx.x * 1024 + tid;
    int val = (i < N_NODES) ? cnt[i] : 0;
    buf[tid] = val;
    __syncthreads();
    for (int off = 1; off < 1024; off <<= 1) {
        int t = (tid >= off) ? buf[tid - off] : 0;
        __syncthreads();
        buf[tid] += t;
        __syncthreads();
    }
    int incl = buf[tid];
    if (i < N_NODES) partial[i] = incl - val;
    if (tid == 1023) bsum[blockIdx.x] = incl;
}

__global__ __launch_bounds__(1024) void scanB_kernel(
    const int* __restrict__ partial, const int* __restrict__ bsum,
    int* __restrict__ offs)
{
    __shared__ int bs[64];
    int tid = threadIdx.x;
    if (tid < SCAN_NB) bs[tid] = bsum[tid];
    __syncthreads();
    if (tid == 0) {
        int run = 0;
        for (int b = 0; b < SCAN_NB; ++b) { int t = bs[b]; bs[b] = run; run += t; }
    }
    __syncthreads();
    for (int i = tid; i < N_NODES; i += 1024) offs[i] = partial[i] + bs[i >> 10];
    if (tid == 0) offs[N_NODES] = N_EDGES;
}

__global__ __launch_bounds__(256) void scatter_kernel(
    const int* __restrict__ src, const int* __restrict__ dst,
    const int* __restrict__ offs, int* __restrict__ cursor,
    int* __restrict__ perm, int* __restrict__ psrc)
{
    int e = blockIdx.x * 256 + threadIdx.x;
    if (e >= N_EDGES) return;
    int d = dst[e];
    int p = atomicAdd(&cursor[d], 1);
    int pos = offs[d] + p;
    perm[pos] = e;
    psrc[pos] = src[e];
}

// attention logits in CSR position order: 32 lanes/edge; k gathered as bf16
__global__ __launch_bounds__(256) void attp_kernel(
    const unsigned short* __restrict__ kh, const float* __restrict__ q,
    const float* __restrict__ relw, const int* __restrict__ perm,
    const int* __restrict__ src, const int* __restrict__ dst,
    const int* __restrict__ etype, float* __restrict__ attp)
{
    const int lane = threadIdx.x & 31;
    const int i = blockIdx.x * 8 + (threadIdx.x >> 5);
    if (i >= N_EDGES) return;
    const int e = perm[i];
    const int s_ = src[e], d_ = dst[e], t_ = etype[e];
    float acc = 0.f;
    if (lane < 25) {
        const ushort4 kt = ((const ushort4*)(kh + (size_t)s_ * 128))[lane];
        const float4 qv = ((const float4*)(q + (size_t)d_ * 100))[lane];
        const float4 wv = ((const float4*)(relw + t_ * 100))[lane];
        acc = bf2f(kt.x) * wv.x * qv.x + bf2f(kt.y) * wv.y * qv.y
            + bf2f(kt.z) * wv.z * qv.z + bf2f(kt.w) * wv.w * qv.w;
    }
    #pragma unroll
    for (int off = 16; off > 0; off >>= 1) acc += __shfl_xor(acc, off, 32);
    if (lane == 0) attp[i] = acc;
}

// one wave per node: softmax + weighted-V aggregate (v bf16) + gated combine
// + BN partials
__global__ __launch_bounds__(256) void agg_kernel(
    const int* __restrict__ offs, const int* __restrict__ psrc,
    const float* __restrict__ attp, const unsigned short* __restrict__ vh,
    const float* __restrict__ alpha, float* __restrict__ out,
    float* __restrict__ bnpart)
{
    __shared__ float ls[100], lq[100];
    const int tid = threadIdx.x;
    if (tid < 100) { ls[tid] = 0.f; lq[tid] = 0.f; }
    __syncthreads();
    const int lane = tid & 63;
    const int gwave = blockIdx.x * 4 + (tid >> 6);
    const int nwaves = AGG_NB * 4;
    const float a = 1.f / (1.f + __expf(-alpha[0]));
    const float b = 1.f - a;
    const int cl = lane;
    const bool act = (cl < 50);
    float sx = 0.f, sy = 0.f, qx = 0.f, qy = 0.f;

    for (int n = gwave; n < N_NODES; n += nwaves) {
        const int beg = offs[n], end = offs[n + 1];
        float m = -INFINITY;
        for (int i = beg + lane; i < end; i += 64) m = fmaxf(m, attp[i]);
        #pragma unroll
        for (int off = 32; off > 0; off >>= 1) m = fmaxf(m, __shfl_xor(m, off, 64));
        float ax = 0.f, ay = 0.f, wsum = 0.f;
        int i = beg;
        for (; i + 4 <= end; i += 4) {
            const int s0 = psrc[i], s1 = psrc[i + 1], s2 = psrc[i + 2], s3 = psrc[i + 3];
            const float w0 = __expf(attp[i] - m),     w1 = __expf(attp[i + 1] - m);
            const float w2 = __expf(attp[i + 2] - m), w3 = __expf(attp[i + 3] - m);
            wsum += w0 + w1 + w2 + w3;
            if (act) {
                const unsigned h0 = ((const unsigned*)(vh + (size_t)s0 * 128))[cl];
                const unsigned h1 = ((const unsigned*)(vh + (size_t)s1 * 128))[cl];
                const unsigned h2 = ((const unsigned*)(vh + (size_t)s2 * 128))[cl];
                const unsigned h3 = ((const unsigned*)(vh + (size_t)s3 * 128))[cl];
                ax += w0 * bf2f((unsigned short)(h0 & 0xFFFFu))
                    + w1 * bf2f((unsigned short)(h1 & 0xFFFFu))
                    + w2 * bf2f((unsigned short)(h2 & 0xFFFFu))
                    + w3 * bf2f((unsigned short)(h3 & 0xFFFFu));
                ay += w0 * bf2f((unsigned short)(h0 >> 16))
                    + w1 * bf2f((unsigned short)(h1 >> 16))
                    + w2 * bf2f((unsigned short)(h2 >> 16))
                    + w3 * bf2f((unsigned short)(h3 >> 16));
            }
        }
        for (; i < end; ++i) {
            const int s0 = psrc[i];
            const float w0 = __expf(attp[i] - m);
            wsum += w0;
            if (act) {
                const unsigned h0 = ((const unsigned*)(vh + (size_t)s0 * 128))[cl];
                ax += w0 * bf2f((unsigned short)(h0 & 0xFFFFu));
                ay += w0 * bf2f((unsigned short)(h0 >> 16));
            }
        }
        const float inv = (wsum > 0.f) ? 1.f / wsum : 0.f;
        if (act) {
            float2* po = (float2*)(out + (size_t)n * 100);
            float2 cur = po[cl];
            float v0 = a * cur.x + b * ax * inv;
            float v1 = a * cur.y + b * ay * inv;
            po[cl] = make_float2(v0, v1);
            sx += v0; qx += v0 * v0;
            sy += v1; qy += v1 * v1;
        }
    }
    if (act) {
        atomicAdd(&ls[2 * cl], sx);     atomicAdd(&ls[2 * cl + 1], sy);
        atomicAdd(&lq[2 * cl], qx);     atomicAdd(&lq[2 * cl + 1], qy);
    }
    __syncthreads();
    if (tid < 100) {
        bnpart[(size_t)tid * AGG_NB + blockIdx.x]         = ls[tid];
        bnpart[(size_t)(tid + 100) * AGG_NB + blockIdx.x] = lq[tid];
    }
}

__global__ __launch_bounds__(256) void bnfin_kernel(
    const float* __restrict__ bnpart,
    const float* __restrict__ gamma, const float* __restrict__ beta,
    float* __restrict__ bnsc, float* __restrict__ bnsh)
{
    const int c = blockIdx.x * 4 + (threadIdx.x >> 6);
    const int lane = threadIdx.x & 63;
    if (c >= 100) return;
    float s = 0.f, q = 0.f;
    for (int b2 = lane; b2 < AGG_NB; b2 += 64) {
        s += bnpart[(size_t)c * AGG_NB + b2];
        q += bnpart[(size_t)(c + 100) * AGG_NB + b2];
    }
    #pragma unroll
    for (int off = 32; off > 0; off >>= 1) {
        s += __shfl_xor(s, off, 64);
        q += __shfl_xor(q, off, 64);
    }
    if (lane == 0) {
        const float inv_n = 1.f / (float)N_NODES;
        float mean = s * inv_n;
        float var = q * inv_n - mean * mean;
        float sc = gamma[c] * rsqrtf(var + BN_EPS);
        bnsc[c] = sc;
        bnsh[c] = beta[c] - mean * sc;
    }
}

__global__ __launch_bounds__(256) void apply_kernel(
    float* __restrict__ out, const float* __restrict__ bnsc,
    const float* __restrict__ bnsh)
{
    const int total4 = N_NODES * 25;
    for (int idx = blockIdx.x * 256 + threadIdx.x; idx < total4; idx += gridDim.x * 256) {
        float4* p = ((float4*)out) + idx;
        const int c = (idx % 25) * 4;
        float4 t = *p;
        t.x = tanhf(t.x * bnsc[c]     + bnsh[c]);
        t.y = tanhf(t.y * bnsc[c + 1] + bnsh[c + 1]);
        t.z = tanhf(t.z * bnsc[c + 2] + bnsh[c + 2]);
        t.w = tanhf(t.w * bnsc[c + 3] + bnsh[c + 3]);
        *p = t;
    }
}

__global__ __launch_bounds__(256) void rout_kernel(
    const float* __restrict__ rf, const float* __restrict__ Wr,
    const float* __restrict__ br, float* __restrict__ out)
{
    int o = blockIdx.x * 256 + threadIdx.x;
    if (o >= 200 * 100) return;
    int r = o / 100, c = o % 100;
    float acc = br[c];
    #pragma unroll 10
    for (int d = 0; d < 100; ++d) acc += rf[r * 100 + d] * Wr[c * 100 + d];
    out[N_NODES * 100 + o] = acc;
}

extern "C" void kernel_launch(void* const* d_in, const int* in_sizes, int n_in,
                              void* d_out, int out_size, void* d_ws, size_t ws_size,
                              hipStream_t stream) {
    const float* X     = (const float*)d_in[0];
    const float* rfeat = (const float*)d_in[1];
    const int*   src   = (const int*)d_in[2];
    const int*   dst   = (const int*)d_in[3];
    const int*   ety   = (const int*)d_in[4];
    const float* Wsw   = (const float*)d_in[6];
    const float* Wsb   = (const float*)d_in[7];
    const float* Wkw   = (const float*)d_in[8];
    const float* Wkb   = (const float*)d_in[9];
    const float* Wqw   = (const float*)d_in[10];
    const float* Wqb   = (const float*)d_in[11];
    const float* Wvw   = (const float*)d_in[12];
    const float* Wvb   = (const float*)d_in[13];
    const float* Wrw   = (const float*)d_in[14];
    const float* Wrb   = (const float*)d_in[15];
    const float* ratt  = (const float*)d_in[16];
    const float* wcomp = (const float*)d_in[17];
    const float* alpha = (const float*)d_in[18];
    const float* gamma = (const float*)d_in[20];
    const float* beta  = (const float*)d_in[21];

    float* out = (float*)d_out;
    float* ws  = (float*)d_ws;
    if (ws_size < (size_t)WS_ELEMS * sizeof(float)) return;

    float* relw        = ws + OFS_RELW;
    unsigned short* kh = (unsigned short*)(ws + OFS_KH);
    float* q           = ws + OFS_Q;
    unsigned short* vh = (unsigned short*)(ws + OFS_VH);
    float* attp        = ws + OFS_ATTP;
    float* bnpart      = ws + OFS_BNPART;
    float* bnsc        = ws + OFS_BNSC;
    float* bnsh        = ws + OFS_BNSH;
    float* Wt          = ws + OFS_WT;
    int* cnt           = (int*)(ws + OFS_CNT);
    int* partial       = (int*)(ws + OFS_PART);
    int* bsum          = (int*)(ws + OFS_BSUM);
    int* offs          = (int*)(ws + OFS_OFFS);
    int* cursor        = (int*)(ws + OFS_CURS);
    int* perm          = (int*)(ws + OFS_PERM);
    int* psrc          = (int*)(ws + OFS_PSRC);

    hipMemsetAsync(cnt, 0, 50000 * sizeof(int), stream);
    hipMemsetAsync(cursor, 0, 50000 * sizeof(int), stream);

    relw_kernel<<<(20000 + 255) / 256, 256, 0, stream>>>(wcomp, ratt, relw);
    wt_kernel<<<(41600 + 255) / 256, 256, 0, stream>>>(Wkw, Wqw, Wvw, Wsw, Wt);
    proj_kernel<<<dim3((N_NODES + 63) / 64, 4), 512, 0, stream>>>(
        X, Wt, Wkb, Wqb, Wvb, Wsb, kh, q, vh, out);

    hist_kernel<<<(N_EDGES + 255) / 256, 256, 0, stream>>>(dst, cnt);
    scanA_kernel<<<SCAN_NB, 1024, 0, stream>>>(cnt, partial, bsum);
    scanB_kernel<<<1, 1024, 0, stream>>>(partial, bsum, offs);
    scatter_kernel<<<(N_EDGES + 255) / 256, 256, 0, stream>>>(src, dst, offs, cursor, perm, psrc);

    attp_kernel<<<(N_EDGES + 7) / 8, 256, 0, stream>>>(
        kh, q, relw, perm, src, dst, ety, attp);
    agg_kernel<<<AGG_NB, 256, 0, stream>>>(offs, psrc, attp, vh, alpha, out, bnpart);
    bnfin_kernel<<<25, 256, 0, stream>>>(bnpart, gamma, beta, bnsc, bnsh);
    apply_kernel<<<2048, 256, 0, stream>>>(out, bnsc, bnsh);
    rout_kernel<<<(20000 + 255) / 256, 256, 0, stream>>>(rfeat, Wrw, Wrb, out);
}

// Round 16
// 334.586 us; speedup vs baseline: 1.2949x; 1.0780x over previous
//
#include <hip/hip_runtime.h>
#include <hip/hip_bf16.h>
#include <math.h>

#define N_NODES 50000
#define N_EDGES 800000
#define BN_EPS  1e-5f
#define SCAN_NB 49     // ceil(50000/1024)
#define AGG_NB  2048   // agg grid blocks

typedef float floatx2 __attribute__((ext_vector_type(2)));

// ---- workspace layout (float-element offsets) ----
#define OFS_RELW   0
#define OFS_KH     20480                 // 50000 * 32 uints (fp8 rows, 128B)
#define OFS_Q      1620480
#define OFS_VH     6620480               // 50000 * 32 uints
#define OFS_ATTP   8220480
#define OFS_BNPART 9020480               // 200 * AGG_NB
#define OFS_BNSC   9430080
#define OFS_BNSH   9430208
#define OFS_CNT    9430336
#define OFS_PART   9480512
#define OFS_BSUM   9530688
#define OFS_OFFS   9530752
#define OFS_CURS   9580928
#define OFS_PSRC   9631104
#define OFS_PDST   10431104
#define OFS_PETY   11231104
#define OFS_WT     12031104              // 4 * 100 * 104 transposed W
#define WS_ELEMS   12072704

// rel_w[r][c] = sum_b w_comp[r][b] * relation_att[b][c]
__global__ __launch_bounds__(256) void relw_kernel(
    const float* __restrict__ wcomp, const float* __restrict__ ratt,
    float* __restrict__ relw)
{
    int o = blockIdx.x * 256 + threadIdx.x;
    if (o >= 200 * 100) return;
    int r = o / 100, c = o % 100;
    float acc = 0.f;
    #pragma unroll 10
    for (int b = 0; b < 50; ++b) acc += wcomp[r * 50 + b] * ratt[b * 100 + c];
    relw[o] = acc;
}

// pre-transpose W to d-major, rows padded to 104: Wt[m][d][c] = Wm[c][d]
__global__ __launch_bounds__(256) void wt_kernel(
    const float* __restrict__ Wk, const float* __restrict__ Wq,
    const float* __restrict__ Wv, const float* __restrict__ Ws,
    float* __restrict__ Wt)
{
    int o = blockIdx.x * 256 + threadIdx.x;
    if (o >= 4 * 100 * 104) return;
    int m = o / 10400, rem = o % 10400, d = rem / 104, c = rem % 104;
    const float* W = (m == 0) ? Wk : (m == 1) ? Wq : (m == 2) ? Wv : Ws;
    Wt[o] = (c < 100) ? W[c * 100 + d] : 0.f;
}

// fused projections (R15 structure: 512 thr, 4x4 tile, d-major W in LDS,
// XOR-swizzled transposed X). m=0 (k) and m=2 (v) now packed to fp8-e4m3
// via HW cvt, rows padded to 128 B (2 aligned cache lines) -> halves the
// random-gather traffic in attp/agg again.
__global__ __launch_bounds__(512) void proj_kernel(
    const float* __restrict__ X, const float* __restrict__ Wt,
    const float* __restrict__ bk, const float* __restrict__ bq,
    const float* __restrict__ bv, const float* __restrict__ bs,
    unsigned* __restrict__ khp, float* __restrict__ qo,
    unsigned* __restrict__ vhp, float* __restrict__ so)
{
    __shared__ float Xt[100][68];    // swizzled transposed X: 27.2 KB
    __shared__ float Wl[100][104];   // d-major W:            41.6 KB
    const int tid = threadIdx.x;
    const int nb  = blockIdx.x * 64;
    const int m   = blockIdx.y;

    const float* bp = (m == 0) ? bk : (m == 1) ? bq : (m == 2) ? bv : bs;

    for (int idx = tid; idx < 2600; idx += 512) {
        int r = idx / 26, c4 = idx % 26;
        float4 w = ((const float4*)(Wt + m * 10400 + r * 104))[c4];
        *(float4*)&Wl[r][c4 * 4] = w;
    }
    for (int idx = tid; idx < 1600; idx += 512) {
        int n = idx / 25, d4 = idx % 25;
        int node = nb + n;
        float4 x = (node < N_NODES)
                   ? ((const float4*)(X + (size_t)node * 100))[d4]
                   : make_float4(0.f, 0.f, 0.f, 0.f);
        const int col = n ^ ((d4 & 7) << 2);
        Xt[4 * d4 + 0][col] = x.x;
        Xt[4 * d4 + 1][col] = x.y;
        Xt[4 * d4 + 2][col] = x.z;
        Xt[4 * d4 + 3][col] = x.w;
    }
    __syncthreads();

    const int nt  = tid & 15;        // node group: nodes 4nt..4nt+3
    const int ct  = tid >> 4;        // col group 0..31 (25 active)
    const bool act = (ct < 25);
    const int cts  = act ? ct : 24;

    float acc[4][4];
    #pragma unroll
    for (int i = 0; i < 4; ++i)
        #pragma unroll
        for (int j = 0; j < 4; ++j) acc[i][j] = 0.f;

    #pragma unroll 4
    for (int d = 0; d < 100; ++d) {
        const int key = ((d >> 2) & 7) << 2;
        const float4 xv = *(const float4*)&Xt[d][(4 * nt) ^ key];
        const float4 wv = *(const float4*)&Wl[d][4 * cts];
        acc[0][0] += xv.x * wv.x; acc[0][1] += xv.x * wv.y;
        acc[0][2] += xv.x * wv.z; acc[0][3] += xv.x * wv.w;
        acc[1][0] += xv.y * wv.x; acc[1][1] += xv.y * wv.y;
        acc[1][2] += xv.y * wv.z; acc[1][3] += xv.y * wv.w;
        acc[2][0] += xv.z * wv.x; acc[2][1] += xv.z * wv.y;
        acc[2][2] += xv.z * wv.z; acc[2][3] += xv.z * wv.w;
        acc[3][0] += xv.w * wv.x; acc[3][1] += xv.w * wv.y;
        acc[3][2] += xv.w * wv.z; acc[3][3] += xv.w * wv.w;
    }

    if (act) {
        const float4 bb = *(const float4*)(bp + ct * 4);
        if (m == 0 || m == 2) {
            unsigned* oph = (m == 0) ? khp : vhp;
            #pragma unroll
            for (int i = 0; i < 4; ++i) {
                const int node = nb + nt * 4 + i;
                if (node < N_NODES) {
                    int wd = 0;
                    wd = __builtin_amdgcn_cvt_pk_fp8_f32(
                        acc[i][0] + bb.x, acc[i][1] + bb.y, wd, false);
                    wd = __builtin_amdgcn_cvt_pk_fp8_f32(
                        acc[i][2] + bb.z, acc[i][3] + bb.w, wd, true);
                    oph[(size_t)node * 32 + ct] = (unsigned)wd;
                }
            }
        } else {
            float* opf = (m == 1) ? qo : so;
            #pragma unroll
            for (int i = 0; i < 4; ++i) {
                const int node = nb + nt * 4 + i;
                if (node < N_NODES) {
                    float4 r = make_float4(acc[i][0] + bb.x, acc[i][1] + bb.y,
                                           acc[i][2] + bb.z, acc[i][3] + bb.w);
                    *(float4*)(opf + (size_t)node * 100 + ct * 4) = r;
                }
            }
        }
    }
}

__global__ __launch_bounds__(256) void hist_kernel(
    const int* __restrict__ dst, int* __restrict__ cnt)
{
    int e = blockIdx.x * 256 + threadIdx.x;
    if (e < N_EDGES) atomicAdd(&cnt[dst[e]], 1);
}

__global__ __launch_bounds__(1024) void scanA_kernel(
    const int* __restrict__ cnt, int* __restrict__ partial, int* __restrict__ bsum)
{
    __shared__ int buf[1024];
    int tid = threadIdx.x;
    int i = blockIdx.x * 1024 + tid;
    int val = (i < N_NODES) ? cnt[i] : 0;
    buf[tid] = val;
    __syncthreads();
    for (int off = 1; off < 1024; off <<= 1) {
        int t = (tid >= off) ? buf[tid - off] : 0;
        __syncthreads();
        buf[tid] += t;
        __syncthreads();
    }
    int incl = buf[tid];
    if (i < N_NODES) partial[i] = incl - val;
    if (tid == 1023) bsum[blockIdx.x] = incl;
}

__global__ __launch_bounds__(1024) void scanB_kernel(
    const int* __restrict__ partial, const int* __restrict__ bsum,
    int* __restrict__ offs)
{
    __shared__ int bs[64];
    int tid = threadIdx.x;
    if (tid < SCAN_NB) bs[tid] = bsum[tid];
    __syncthreads();
    if (tid == 0) {
        int run = 0;
        for (int b = 0; b < SCAN_NB; ++b) { int t = bs[b]; bs[b] = run; run += t; }
    }
    __syncthreads();
    for (int i = tid; i < N_NODES; i += 1024) offs[i] = partial[i] + bs[i >> 10];
    if (tid == 0) offs[N_NODES] = N_EDGES;
}

// scatter sorted copies of src/dst/etype (no perm indirection downstream)
__global__ __launch_bounds__(256) void scatter_kernel(
    const int* __restrict__ src, const int* __restrict__ dst,
    const int* __restrict__ ety, const int* __restrict__ offs,
    int* __restrict__ cursor, int* __restrict__ psrc,
    int* __restrict__ pdst, int* __restrict__ pety)
{
    int e = blockIdx.x * 256 + threadIdx.x;
    if (e >= N_EDGES) return;
    int d = dst[e];
    int p = atomicAdd(&cursor[d], 1);
    int pos = offs[d] + p;
    psrc[pos] = src[e];
    pdst[pos] = d;
    pety[pos] = ety[e];
}

// attention logits in CSR position order: 32 lanes/edge; sequential index
// reads (psrc/pdst/pety), k gathered as fp8-e4m3 (128B rows, 2 lines).
__global__ __launch_bounds__(256) void attp_kernel(
    const unsigned* __restrict__ khp, const float* __restrict__ q,
    const float* __restrict__ relw, const int* __restrict__ psrc,
    const int* __restrict__ pdst, const int* __restrict__ pety,
    float* __restrict__ attp)
{
    const int lane = threadIdx.x & 31;
    const int i = blockIdx.x * 8 + (threadIdx.x >> 5);
    if (i >= N_EDGES) return;
    const int s_ = psrc[i], d_ = pdst[i], t_ = pety[i];
    float acc = 0.f;
    if (lane < 25) {
        const unsigned kw = (khp + (size_t)s_ * 32)[lane];
        const floatx2 k01 = __builtin_amdgcn_cvt_pk_f32_fp8((int)kw, false);
        const floatx2 k23 = __builtin_amdgcn_cvt_pk_f32_fp8((int)kw, true);
        const float4 qv = ((const float4*)(q + (size_t)d_ * 100))[lane];
        const float4 wv = ((const float4*)(relw + t_ * 100))[lane];
        acc = k01[0] * wv.x * qv.x + k01[1] * wv.y * qv.y
            + k23[0] * wv.z * qv.z + k23[1] * wv.w * qv.w;
    }
    #pragma unroll
    for (int off = 16; off > 0; off >>= 1) acc += __shfl_xor(acc, off, 32);
    if (lane == 0) attp[i] = acc;
}

// one wave per node: softmax + weighted-V aggregate (v fp8) + gated combine
// + BN partials
__global__ __launch_bounds__(256) void agg_kernel(
    const int* __restrict__ offs, const int* __restrict__ psrc,
    const float* __restrict__ attp, const unsigned short* __restrict__ vhp,
    const float* __restrict__ alpha, float* __restrict__ out,
    float* __restrict__ bnpart)
{
    __shared__ float ls[100], lq[100];
    const int tid = threadIdx.x;
    if (tid < 100) { ls[tid] = 0.f; lq[tid] = 0.f; }
    __syncthreads();
    const int lane = tid & 63;
    const int gwave = blockIdx.x * 4 + (tid >> 6);
    const int nwaves = AGG_NB * 4;
    const float a = 1.f / (1.f + __expf(-alpha[0]));
    const float b = 1.f - a;
    const int cl = lane;             // lane owns columns 2cl, 2cl+1
    const bool act = (cl < 50);
    float sx = 0.f, sy = 0.f, qx = 0.f, qy = 0.f;

    for (int n = gwave; n < N_NODES; n += nwaves) {
        const int beg = offs[n], end = offs[n + 1];
        float m = -INFINITY;
        for (int i = beg + lane; i < end; i += 64) m = fmaxf(m, attp[i]);
        #pragma unroll
        for (int off = 32; off > 0; off >>= 1) m = fmaxf(m, __shfl_xor(m, off, 64));
        float ax = 0.f, ay = 0.f, wsum = 0.f;
        int i = beg;
        for (; i + 4 <= end; i += 4) {
            const int s0 = psrc[i], s1 = psrc[i + 1], s2 = psrc[i + 2], s3 = psrc[i + 3];
            const float w0 = __expf(attp[i] - m),     w1 = __expf(attp[i + 1] - m);
            const float w2 = __expf(attp[i + 2] - m), w3 = __expf(attp[i + 3] - m);
            wsum += w0 + w1 + w2 + w3;
            if (act) {
                const unsigned short h0 = vhp[(size_t)s0 * 64 + cl];
                const unsigned short h1 = vhp[(size_t)s1 * 64 + cl];
                const unsigned short h2 = vhp[(size_t)s2 * 64 + cl];
                const unsigned short h3 = vhp[(size_t)s3 * 64 + cl];
                const floatx2 v0 = __builtin_amdgcn_cvt_pk_f32_fp8((int)h0, false);
                const floatx2 v1 = __builtin_amdgcn_cvt_pk_f32_fp8((int)h1, false);
                const floatx2 v2 = __builtin_amdgcn_cvt_pk_f32_fp8((int)h2, false);
                const floatx2 v3 = __builtin_amdgcn_cvt_pk_f32_fp8((int)h3, false);
                ax += w0 * v0[0] + w1 * v1[0] + w2 * v2[0] + w3 * v3[0];
                ay += w0 * v0[1] + w1 * v1[1] + w2 * v2[1] + w3 * v3[1];
            }
        }
        for (; i < end; ++i) {
            const int s0 = psrc[i];
            const float w0 = __expf(attp[i] - m);
            wsum += w0;
            if (act) {
                const unsigned short h0 = vhp[(size_t)s0 * 64 + cl];
                const floatx2 v0 = __builtin_amdgcn_cvt_pk_f32_fp8((int)h0, false);
                ax += w0 * v0[0];
                ay += w0 * v0[1];
            }
        }
        const float inv = (wsum > 0.f) ? 1.f / wsum : 0.f;
        if (act) {
            float2* po = (float2*)(out + (size_t)n * 100);
            float2 cur = po[cl];
            float v0 = a * cur.x + b * ax * inv;
            float v1 = a * cur.y + b * ay * inv;
            po[cl] = make_float2(v0, v1);
            sx += v0; qx += v0 * v0;
            sy += v1; qy += v1 * v1;
        }
    }
    if (act) {
        atomicAdd(&ls[2 * cl], sx);     atomicAdd(&ls[2 * cl + 1], sy);
        atomicAdd(&lq[2 * cl], qx);     atomicAdd(&lq[2 * cl + 1], qy);
    }
    __syncthreads();
    if (tid < 100) {
        bnpart[(size_t)tid * AGG_NB + blockIdx.x]         = ls[tid];
        bnpart[(size_t)(tid + 100) * AGG_NB + blockIdx.x] = lq[tid];
    }
}

__global__ __launch_bounds__(256) void bnfin_kernel(
    const float* __restrict__ bnpart,
    const float* __restrict__ gamma, const float* __restrict__ beta,
    float* __restrict__ bnsc, float* __restrict__ bnsh)
{
    const int c = blockIdx.x * 4 + (threadIdx.x >> 6);
    const int lane = threadIdx.x & 63;
    if (c >= 100) return;
    float s = 0.f, q = 0.f;
    for (int b2 = lane; b2 < AGG_NB; b2 += 64) {
        s += bnpart[(size_t)c * AGG_NB + b2];
        q += bnpart[(size_t)(c + 100) * AGG_NB + b2];
    }
    #pragma unroll
    for (int off = 32; off > 0; off >>= 1) {
        s += __shfl_xor(s, off, 64);
        q += __shfl_xor(q, off, 64);
    }
    if (lane == 0) {
        const float inv_n = 1.f / (float)N_NODES;
        float mean = s * inv_n;
        float var = q * inv_n - mean * mean;
        float sc = gamma[c] * rsqrtf(var + BN_EPS);
        bnsc[c] = sc;
        bnsh[c] = beta[c] - mean * sc;
    }
}

__global__ __launch_bounds__(256) void apply_kernel(
    float* __restrict__ out, const float* __restrict__ bnsc,
    const float* __restrict__ bnsh)
{
    const int total4 = N_NODES * 25;
    for (int idx = blockIdx.x * 256 + threadIdx.x; idx < total4; idx += gridDim.x * 256) {
        float4* p = ((float4*)out) + idx;
        const int c = (idx % 25) * 4;
        float4 t = *p;
        t.x = tanhf(t.x * bnsc[c]     + bnsh[c]);
        t.y = tanhf(t.y * bnsc[c + 1] + bnsh[c + 1]);
        t.z = tanhf(t.z * bnsc[c + 2] + bnsh[c + 2]);
        t.w = tanhf(t.w * bnsc[c + 3] + bnsh[c + 3]);
        *p = t;
    }
}

__global__ __launch_bounds__(256) void rout_kernel(
    const float* __restrict__ rf, const float* __restrict__ Wr,
    const float* __restrict__ br, float* __restrict__ out)
{
    int o = blockIdx.x * 256 + threadIdx.x;
    if (o >= 200 * 100) return;
    int r = o / 100, c = o % 100;
    float acc = br[c];
    #pragma unroll 10
    for (int d = 0; d < 100; ++d) acc += rf[r * 100 + d] * Wr[c * 100 + d];
    out[N_NODES * 100 + o] = acc;
}

extern "C" void kernel_launch(void* const* d_in, const int* in_sizes, int n_in,
                              void* d_out, int out_size, void* d_ws, size_t ws_size,
                              hipStream_t stream) {
    const float* X     = (const float*)d_in[0];
    const float* rfeat = (const float*)d_in[1];
    const int*   src   = (const int*)d_in[2];
    const int*   dst   = (const int*)d_in[3];
    const int*   ety   = (const int*)d_in[4];
    const float* Wsw   = (const float*)d_in[6];
    const float* Wsb   = (const float*)d_in[7];
    const float* Wkw   = (const float*)d_in[8];
    const float* Wkb   = (const float*)d_in[9];
    const float* Wqw   = (const float*)d_in[10];
    const float* Wqb   = (const float*)d_in[11];
    const float* Wvw   = (const float*)d_in[12];
    const float* Wvb   = (const float*)d_in[13];
    const float* Wrw   = (const float*)d_in[14];
    const float* Wrb   = (const float*)d_in[15];
    const float* ratt  = (const float*)d_in[16];
    const float* wcomp = (const float*)d_in[17];
    const float* alpha = (const float*)d_in[18];
    const float* gamma = (const float*)d_in[20];
    const float* beta  = (const float*)d_in[21];

    float* out = (float*)d_out;
    float* ws  = (float*)d_ws;
    if (ws_size < (size_t)WS_ELEMS * sizeof(float)) return;

    float* relw          = ws + OFS_RELW;
    unsigned* khp        = (unsigned*)(ws + OFS_KH);
    float* q             = ws + OFS_Q;
    unsigned* vhp        = (unsigned*)(ws + OFS_VH);
    float* attp          = ws + OFS_ATTP;
    float* bnpart        = ws + OFS_BNPART;
    float* bnsc          = ws + OFS_BNSC;
    float* bnsh          = ws + OFS_BNSH;
    float* Wt            = ws + OFS_WT;
    int* cnt             = (int*)(ws + OFS_CNT);
    int* partial         = (int*)(ws + OFS_PART);
    int* bsum            = (int*)(ws + OFS_BSUM);
    int* offs            = (int*)(ws + OFS_OFFS);
    int* cursor          = (int*)(ws + OFS_CURS);
    int* psrc            = (int*)(ws + OFS_PSRC);
    int* pdst            = (int*)(ws + OFS_PDST);
    int* pety            = (int*)(ws + OFS_PETY);

    hipMemsetAsync(cnt, 0, 50000 * sizeof(int), stream);
    hipMemsetAsync(cursor, 0, 50000 * sizeof(int), stream);

    relw_kernel<<<(20000 + 255) / 256, 256, 0, stream>>>(wcomp, ratt, relw);
    wt_kernel<<<(41600 + 255) / 256, 256, 0, stream>>>(Wkw, Wqw, Wvw, Wsw, Wt);
    proj_kernel<<<dim3((N_NODES + 63) / 64, 4), 512, 0, stream>>>(
        X, Wt, Wkb, Wqb, Wvb, Wsb, khp, q, vhp, out);

    hist_kernel<<<(N_EDGES + 255) / 256, 256, 0, stream>>>(dst, cnt);
    scanA_kernel<<<SCAN_NB, 1024, 0, stream>>>(cnt, partial, bsum);
    scanB_kernel<<<1, 1024, 0, stream>>>(partial, bsum, offs);
    scatter_kernel<<<(N_EDGES + 255) / 256, 256, 0, stream>>>(
        src, dst, ety, offs, cursor, psrc, pdst, pety);

    attp_kernel<<<(N_EDGES + 7) / 8, 256, 0, stream>>>(
        khp, q, relw, psrc, pdst, pety, attp);
    agg_kernel<<<AGG_NB, 256, 0, stream>>>(
        offs, psrc, attp, (const unsigned short*)vhp, alpha, out, bnpart);
    bnfin_kernel<<<25, 256, 0, stream>>>(bnpart, gamma, beta, bnsc, bnsh);
    apply_kernel<<<2048, 256, 0, stream>>>(out, bnsc, bnsh);
    rout_kernel<<<(20000 + 255) / 256, 256, 0, stream>>>(rfeat, Wrw, Wrb, out);
}

// Round 17
// 320.208 us; speedup vs baseline: 1.3530x; 1.0449x over previous
//
#include <hip/hip_runtime.h>
#include <hip/hip_bf16.h>
#include <math.h>

#define N_NODES 50000
#define N_EDGES 800000
#define BN_EPS  1e-5f
#define SCAN_NB 49     // ceil(50000/1024)
#define AGG_NB  2048   // agg grid blocks

typedef float floatx2 __attribute__((ext_vector_type(2)));
typedef _Float16 half2_t __attribute__((ext_vector_type(2)));

#if defined(__has_builtin) && __has_builtin(__builtin_amdgcn_fdot2)
#define FDOT2(a, b, c) __builtin_amdgcn_fdot2((a), (b), (c), false)
#else
#define FDOT2(a, b, c) ((c) + (float)(a).x * (float)(b).x + (float)(a).y * (float)(b).y)
#endif

union h2u { half2_t h; unsigned u; };

// ---- workspace layout (float-element offsets) ----
#define OFS_RELW   0
#define OFS_KH     20480                 // 50000 * 32 uints (fp8 rows, 128B)
#define OFS_Q      1620480
#define OFS_VH     6620480               // 50000 * 32 uints
#define OFS_ATTP   8220480
#define OFS_BNPART 9020480               // 200 * AGG_NB
#define OFS_BNSC   9430080
#define OFS_BNSH   9430208
#define OFS_CNT    9430336
#define OFS_PART   9480512
#define OFS_BSUM   9530688
#define OFS_OFFS   9530752
#define OFS_CURS   9580928
#define OFS_PSRC   9631104
#define OFS_PDST   10431104
#define OFS_PETY   11231104
#define OFS_WT     12031104              // 4 * 50 * 104 packed-half2 W
#define WS_ELEMS   12072704

// rel_w[r][c] = sum_b w_comp[r][b] * relation_att[b][c]
__global__ __launch_bounds__(256) void relw_kernel(
    const float* __restrict__ wcomp, const float* __restrict__ ratt,
    float* __restrict__ relw)
{
    int o = blockIdx.x * 256 + threadIdx.x;
    if (o >= 200 * 100) return;
    int r = o / 100, c = o % 100;
    float acc = 0.f;
    #pragma unroll 10
    for (int b = 0; b < 50; ++b) acc += wcomp[r * 50 + b] * ratt[b * 100 + c];
    relw[o] = acc;
}

// pack W to d-pair-major half2: Wth[m][d2][c] = (half)W[c][2d2], (half)W[c][2d2+1]
__global__ __launch_bounds__(256) void wth_kernel(
    const float* __restrict__ Wk, const float* __restrict__ Wq,
    const float* __restrict__ Wv, const float* __restrict__ Ws,
    unsigned* __restrict__ Wth)
{
    int o = blockIdx.x * 256 + threadIdx.x;
    if (o >= 4 * 50 * 104) return;
    int m = o / 5200, rem = o % 5200, d2 = rem / 104, c = rem % 104;
    const float* W = (m == 0) ? Wk : (m == 1) ? Wq : (m == 2) ? Wv : Ws;
    float a = (c < 100) ? W[c * 100 + 2 * d2]     : 0.f;
    float b = (c < 100) ? W[c * 100 + 2 * d2 + 1] : 0.f;
    h2u cv; cv.h = half2_t{(_Float16)a, (_Float16)b};
    Wth[o] = cv.u;
}

// fused projections: R15 geometry (512 thr, 4x4 tile, 64-node tile, XOR
// swizzle) with LDS elements = packed half2 along d. One X b128 + one W
// b128 feeds TWO d-steps via v_dot2_f32_f16 -> LDS read traffic and VALU
// op count both halve; LDS 34.4 KB -> 4 blocks/CU (32 waves, 2x occupancy).
// m=0 (k) and m=2 (v) packed to fp8-e4m3 (128B rows); q,s stay fp32.
__global__ __launch_bounds__(512) void proj_kernel(
    const float* __restrict__ X, const unsigned* __restrict__ Wth,
    const float* __restrict__ bk, const float* __restrict__ bq,
    const float* __restrict__ bv, const float* __restrict__ bs,
    unsigned* __restrict__ khp, float* __restrict__ qo,
    unsigned* __restrict__ vhp, float* __restrict__ so)
{
    __shared__ unsigned Xth[50][68];    // 13.6 KB, swizzled transposed X (half2)
    __shared__ unsigned Wlh[50][104];   // 20.8 KB, d-pair-major W (half2)
    const int tid = threadIdx.x;
    const int nb  = blockIdx.x * 64;
    const int m   = blockIdx.y;

    const float* bp = (m == 0) ? bk : (m == 1) ? bq : (m == 2) ? bv : bs;

    // stage W: 50 rows x 26 uint4, coalesced from pre-packed global
    for (int idx = tid; idx < 1300; idx += 512) {
        int r = idx / 26, c4 = idx % 26;
        uint4 w = ((const uint4*)(Wth + m * 5200 + r * 104))[c4];
        *(uint4*)&Wlh[r][c4 * 4] = w;
    }
    // stage X transposed + packed to half2 + XOR-swizzled columns
    for (int idx = tid; idx < 1600; idx += 512) {
        int n = idx / 25, d4 = idx % 25;
        int node = nb + n;
        float4 x = (node < N_NODES)
                   ? ((const float4*)(X + (size_t)node * 100))[d4]
                   : make_float4(0.f, 0.f, 0.f, 0.f);
        const int col = n ^ ((d4 & 7) << 2);
        h2u c0, c1;
        c0.h = half2_t{(_Float16)x.x, (_Float16)x.y};
        c1.h = half2_t{(_Float16)x.z, (_Float16)x.w};
        Xth[2 * d4][col]     = c0.u;
        Xth[2 * d4 + 1][col] = c1.u;
    }
    __syncthreads();

    const int nt  = tid & 15;        // node group: nodes 4nt..4nt+3
    const int ct  = tid >> 4;        // col group 0..31 (25 active)
    const bool act = (ct < 25);
    const int cts  = act ? ct : 24;

    float acc[4][4];
    #pragma unroll
    for (int i = 0; i < 4; ++i)
        #pragma unroll
        for (int j = 0; j < 4; ++j) acc[i][j] = 0.f;

    #pragma unroll 5
    for (int d2 = 0; d2 < 50; ++d2) {
        const int key = ((d2 >> 1) & 7) << 2;
        const uint4 xv = *(const uint4*)&Xth[d2][(4 * nt) ^ key];
        const uint4 wv = *(const uint4*)&Wlh[d2][4 * cts];
        h2u x0, x1, x2, x3, w0, w1, w2, w3;
        x0.u = xv.x; x1.u = xv.y; x2.u = xv.z; x3.u = xv.w;
        w0.u = wv.x; w1.u = wv.y; w2.u = wv.z; w3.u = wv.w;
        acc[0][0] = FDOT2(x0.h, w0.h, acc[0][0]);
        acc[0][1] = FDOT2(x0.h, w1.h, acc[0][1]);
        acc[0][2] = FDOT2(x0.h, w2.h, acc[0][2]);
        acc[0][3] = FDOT2(x0.h, w3.h, acc[0][3]);
        acc[1][0] = FDOT2(x1.h, w0.h, acc[1][0]);
        acc[1][1] = FDOT2(x1.h, w1.h, acc[1][1]);
        acc[1][2] = FDOT2(x1.h, w2.h, acc[1][2]);
        acc[1][3] = FDOT2(x1.h, w3.h, acc[1][3]);
        acc[2][0] = FDOT2(x2.h, w0.h, acc[2][0]);
        acc[2][1] = FDOT2(x2.h, w1.h, acc[2][1]);
        acc[2][2] = FDOT2(x2.h, w2.h, acc[2][2]);
        acc[2][3] = FDOT2(x2.h, w3.h, acc[2][3]);
        acc[3][0] = FDOT2(x3.h, w0.h, acc[3][0]);
        acc[3][1] = FDOT2(x3.h, w1.h, acc[3][1]);
        acc[3][2] = FDOT2(x3.h, w2.h, acc[3][2]);
        acc[3][3] = FDOT2(x3.h, w3.h, acc[3][3]);
    }

    if (act) {
        const float4 bb = *(const float4*)(bp + ct * 4);
        if (m == 0 || m == 2) {
            unsigned* oph = (m == 0) ? khp : vhp;
            #pragma unroll
            for (int i = 0; i < 4; ++i) {
                const int node = nb + nt * 4 + i;
                if (node < N_NODES) {
                    int wd = 0;
                    wd = __builtin_amdgcn_cvt_pk_fp8_f32(
                        acc[i][0] + bb.x, acc[i][1] + bb.y, wd, false);
                    wd = __builtin_amdgcn_cvt_pk_fp8_f32(
                        acc[i][2] + bb.z, acc[i][3] + bb.w, wd, true);
                    oph[(size_t)node * 32 + ct] = (unsigned)wd;
                }
            }
        } else {
            float* opf = (m == 1) ? qo : so;
            #pragma unroll
            for (int i = 0; i < 4; ++i) {
                const int node = nb + nt * 4 + i;
                if (node < N_NODES) {
                    float4 r = make_float4(acc[i][0] + bb.x, acc[i][1] + bb.y,
                                           acc[i][2] + bb.z, acc[i][3] + bb.w);
                    *(float4*)(opf + (size_t)node * 100 + ct * 4) = r;
                }
            }
        }
    }
}

__global__ __launch_bounds__(256) void hist_kernel(
    const int* __restrict__ dst, int* __restrict__ cnt)
{
    int e = blockIdx.x * 256 + threadIdx.x;
    if (e < N_EDGES) atomicAdd(&cnt[dst[e]], 1);
}

__global__ __launch_bounds__(1024) void scanA_kernel(
    const int* __restrict__ cnt, int* __restrict__ partial, int* __restrict__ bsum)
{
    __shared__ int buf[1024];
    int tid = threadIdx.x;
    int i = blockIdx.x * 1024 + tid;
    int val = (i < N_NODES) ? cnt[i] : 0;
    buf[tid] = val;
    __syncthreads();
    for (int off = 1; off < 1024; off <<= 1) {
        int t = (tid >= off) ? buf[tid - off] : 0;
        __syncthreads();
        buf[tid] += t;
        __syncthreads();
    }
    int incl = buf[tid];
    if (i < N_NODES) partial[i] = incl - val;
    if (tid == 1023) bsum[blockIdx.x] = incl;
}

__global__ __launch_bounds__(1024) void scanB_kernel(
    const int* __restrict__ partial, const int* __restrict__ bsum,
    int* __restrict__ offs)
{
    __shared__ int bs[64];
    int tid = threadIdx.x;
    if (tid < SCAN_NB) bs[tid] = bsum[tid];
    __syncthreads();
    if (tid == 0) {
        int run = 0;
        for (int b = 0; b < SCAN_NB; ++b) { int t = bs[b]; bs[b] = run; run += t; }
    }
    __syncthreads();
    for (int i = tid; i < N_NODES; i += 1024) offs[i] = partial[i] + bs[i >> 10];
    if (tid == 0) offs[N_NODES] = N_EDGES;
}

// scatter sorted copies of src/dst/etype (no perm indirection downstream)
__global__ __launch_bounds__(256) void scatter_kernel(
    const int* __restrict__ src, const int* __restrict__ dst,
    const int* __restrict__ ety, const int* __restrict__ offs,
    int* __restrict__ cursor, int* __restrict__ psrc,
    int* __restrict__ pdst, int* __restrict__ pety)
{
    int e = blockIdx.x * 256 + threadIdx.x;
    if (e >= N_EDGES) return;
    int d = dst[e];
    int p = atomicAdd(&cursor[d], 1);
    int pos = offs[d] + p;
    psrc[pos] = src[e];
    pdst[pos] = d;
    pety[pos] = ety[e];
}

// attention logits in CSR position order: 32 lanes/edge; sequential index
// reads (psrc/pdst/pety), k gathered as fp8-e4m3 (128B rows, 2 lines).
__global__ __launch_bounds__(256) void attp_kernel(
    const unsigned* __restrict__ khp, const float* __restrict__ q,
    const float* __restrict__ relw, const int* __restrict__ psrc,
    const int* __restrict__ pdst, const int* __restrict__ pety,
    float* __restrict__ attp)
{
    const int lane = threadIdx.x & 31;
    const int i = blockIdx.x * 8 + (threadIdx.x >> 5);
    if (i >= N_EDGES) return;
    const int s_ = psrc[i], d_ = pdst[i], t_ = pety[i];
    float acc = 0.f;
    if (lane < 25) {
        const unsigned kw = (khp + (size_t)s_ * 32)[lane];
        const floatx2 k01 = __builtin_amdgcn_cvt_pk_f32_fp8((int)kw, false);
        const floatx2 k23 = __builtin_amdgcn_cvt_pk_f32_fp8((int)kw, true);
        const float4 qv = ((const float4*)(q + (size_t)d_ * 100))[lane];
        const float4 wv = ((const float4*)(relw + t_ * 100))[lane];
        acc = k01[0] * wv.x * qv.x + k01[1] * wv.y * qv.y
            + k23[0] * wv.z * qv.z + k23[1] * wv.w * qv.w;
    }
    #pragma unroll
    for (int off = 16; off > 0; off >>= 1) acc += __shfl_xor(acc, off, 32);
    if (lane == 0) attp[i] = acc;
}

// one wave per node: softmax + weighted-V aggregate (v fp8) + gated combine
// + BN partials
__global__ __launch_bounds__(256) void agg_kernel(
    const int* __restrict__ offs, const int* __restrict__ psrc,
    const float* __restrict__ attp, const unsigned short* __restrict__ vhp,
    const float* __restrict__ alpha, float* __restrict__ out,
    float* __restrict__ bnpart)
{
    __shared__ float ls[100], lq[100];
    const int tid = threadIdx.x;
    if (tid < 100) { ls[tid] = 0.f; lq[tid] = 0.f; }
    __syncthreads();
    const int lane = tid & 63;
    const int gwave = blockIdx.x * 4 + (tid >> 6);
    const int nwaves = AGG_NB * 4;
    const float a = 1.f / (1.f + __expf(-alpha[0]));
    const float b = 1.f - a;
    const int cl = lane;             // lane owns columns 2cl, 2cl+1
    const bool act = (cl < 50);
    float sx = 0.f, sy = 0.f, qx = 0.f, qy = 0.f;

    for (int n = gwave; n < N_NODES; n += nwaves) {
        const int beg = offs[n], end = offs[n + 1];
        float m = -INFINITY;
        for (int i = beg + lane; i < end; i += 64) m = fmaxf(m, attp[i]);
        #pragma unroll
        for (int off = 32; off > 0; off >>= 1) m = fmaxf(m, __shfl_xor(m, off, 64));
        float ax = 0.f, ay = 0.f, wsum = 0.f;
        int i = beg;
        for (; i + 4 <= end; i += 4) {
            const int s0 = psrc[i], s1 = psrc[i + 1], s2 = psrc[i + 2], s3 = psrc[i + 3];
            const float w0 = __expf(attp[i] - m),     w1 = __expf(attp[i + 1] - m);
            const float w2 = __expf(attp[i + 2] - m), w3 = __expf(attp[i + 3] - m);
            wsum += w0 + w1 + w2 + w3;
            if (act) {
                const unsigned short h0 = vhp[(size_t)s0 * 64 + cl];
                const unsigned short h1 = vhp[(size_t)s1 * 64 + cl];
                const unsigned short h2 = vhp[(size_t)s2 * 64 + cl];
                const unsigned short h3 = vhp[(size_t)s3 * 64 + cl];
                const floatx2 v0 = __builtin_amdgcn_cvt_pk_f32_fp8((int)h0, false);
                const floatx2 v1 = __builtin_amdgcn_cvt_pk_f32_fp8((int)h1, false);
                const floatx2 v2 = __builtin_amdgcn_cvt_pk_f32_fp8((int)h2, false);
                const floatx2 v3 = __builtin_amdgcn_cvt_pk_f32_fp8((int)h3, false);
                ax += w0 * v0[0] + w1 * v1[0] + w2 * v2[0] + w3 * v3[0];
                ay += w0 * v0[1] + w1 * v1[1] + w2 * v2[1] + w3 * v3[1];
            }
        }
        for (; i < end; ++i) {
            const int s0 = psrc[i];
            const float w0 = __expf(attp[i] - m);
            wsum += w0;
            if (act) {
                const unsigned short h0 = vhp[(size_t)s0 * 64 + cl];
                const floatx2 v0 = __builtin_amdgcn_cvt_pk_f32_fp8((int)h0, false);
                ax += w0 * v0[0];
                ay += w0 * v0[1];
            }
        }
        const float inv = (wsum > 0.f) ? 1.f / wsum : 0.f;
        if (act) {
            float2* po = (float2*)(out + (size_t)n * 100);
            float2 cur = po[cl];
            float v0 = a * cur.x + b * ax * inv;
            float v1 = a * cur.y + b * ay * inv;
            po[cl] = make_float2(v0, v1);
            sx += v0; qx += v0 * v0;
            sy += v1; qy += v1 * v1;
        }
    }
    if (act) {
        atomicAdd(&ls[2 * cl], sx);     atomicAdd(&ls[2 * cl + 1], sy);
        atomicAdd(&lq[2 * cl], qx);     atomicAdd(&lq[2 * cl + 1], qy);
    }
    __syncthreads();
    if (tid < 100) {
        bnpart[(size_t)tid * AGG_NB + blockIdx.x]         = ls[tid];
        bnpart[(size_t)(tid + 100) * AGG_NB + blockIdx.x] = lq[tid];
    }
}

__global__ __launch_bounds__(256) void bnfin_kernel(
    const float* __restrict__ bnpart,
    const float* __restrict__ gamma, const float* __restrict__ beta,
    float* __restrict__ bnsc, float* __restrict__ bnsh)
{
    const int c = blockIdx.x * 4 + (threadIdx.x >> 6);
    const int lane = threadIdx.x & 63;
    if (c >= 100) return;
    float s = 0.f, q = 0.f;
    for (int b2 = lane; b2 < AGG_NB; b2 += 64) {
        s += bnpart[(size_t)c * AGG_NB + b2];
        q += bnpart[(size_t)(c + 100) * AGG_NB + b2];
    }
    #pragma unroll
    for (int off = 32; off > 0; off >>= 1) {
        s += __shfl_xor(s, off, 64);
        q += __shfl_xor(q, off, 64);
    }
    if (lane == 0) {
        const float inv_n = 1.f / (float)N_NODES;
        float mean = s * inv_n;
        float var = q * inv_n - mean * mean;
        float sc = gamma[c] * rsqrtf(var + BN_EPS);
        bnsc[c] = sc;
        bnsh[c] = beta[c] - mean * sc;
    }
}

__global__ __launch_bounds__(256) void apply_kernel(
    float* __restrict__ out, const float* __restrict__ bnsc,
    const float* __restrict__ bnsh)
{
    const int total4 = N_NODES * 25;
    for (int idx = blockIdx.x * 256 + threadIdx.x; idx < total4; idx += gridDim.x * 256) {
        float4* p = ((float4*)out) + idx;
        const int c = (idx % 25) * 4;
        float4 t = *p;
        t.x = tanhf(t.x * bnsc[c]     + bnsh[c]);
        t.y = tanhf(t.y * bnsc[c + 1] + bnsh[c + 1]);
        t.z = tanhf(t.z * bnsc[c + 2] + bnsh[c + 2]);
        t.w = tanhf(t.w * bnsc[c + 3] + bnsh[c + 3]);
        *p = t;
    }
}

__global__ __launch_bounds__(256) void rout_kernel(
    const float* __restrict__ rf, const float* __restrict__ Wr,
    const float* __restrict__ br, float* __restrict__ out)
{
    int o = blockIdx.x * 256 + threadIdx.x;
    if (o >= 200 * 100) return;
    int r = o / 100, c = o % 100;
    float acc = br[c];
    #pragma unroll 10
    for (int d = 0; d < 100; ++d) acc += rf[r * 100 + d] * Wr[c * 100 + d];
    out[N_NODES * 100 + o] = acc;
}

extern "C" void kernel_launch(void* const* d_in, const int* in_sizes, int n_in,
                              void* d_out, int out_size, void* d_ws, size_t ws_size,
                              hipStream_t stream) {
    const float* X     = (const float*)d_in[0];
    const float* rfeat = (const float*)d_in[1];
    const int*   src   = (const int*)d_in[2];
    const int*   dst   = (const int*)d_in[3];
    const int*   ety   = (const int*)d_in[4];
    const float* Wsw   = (const float*)d_in[6];
    const float* Wsb   = (const float*)d_in[7];
    const float* Wkw   = (const float*)d_in[8];
    const float* Wkb   = (const float*)d_in[9];
    const float* Wqw   = (const float*)d_in[10];
    const float* Wqb   = (const float*)d_in[11];
    const float* Wvw   = (const float*)d_in[12];
    const float* Wvb   = (const float*)d_in[13];
    const float* Wrw   = (const float*)d_in[14];
    const float* Wrb   = (const float*)d_in[15];
    const float* ratt  = (const float*)d_in[16];
    const float* wcomp = (const float*)d_in[17];
    const float* alpha = (const float*)d_in[18];
    const float* gamma = (const float*)d_in[20];
    const float* beta  = (const float*)d_in[21];

    float* out = (float*)d_out;
    float* ws  = (float*)d_ws;
    if (ws_size < (size_t)WS_ELEMS * sizeof(float)) return;

    float* relw          = ws + OFS_RELW;
    unsigned* khp        = (unsigned*)(ws + OFS_KH);
    float* q             = ws + OFS_Q;
    unsigned* vhp        = (unsigned*)(ws + OFS_VH);
    float* attp          = ws + OFS_ATTP;
    float* bnpart        = ws + OFS_BNPART;
    float* bnsc          = ws + OFS_BNSC;
    float* bnsh          = ws + OFS_BNSH;
    unsigned* Wth        = (unsigned*)(ws + OFS_WT);
    int* cnt             = (int*)(ws + OFS_CNT);
    int* partial         = (int*)(ws + OFS_PART);
    int* bsum            = (int*)(ws + OFS_BSUM);
    int* offs            = (int*)(ws + OFS_OFFS);
    int* cursor          = (int*)(ws + OFS_CURS);
    int* psrc            = (int*)(ws + OFS_PSRC);
    int* pdst            = (int*)(ws + OFS_PDST);
    int* pety            = (int*)(ws + OFS_PETY);

    hipMemsetAsync(cnt, 0, 50000 * sizeof(int), stream);
    hipMemsetAsync(cursor, 0, 50000 * sizeof(int), stream);

    relw_kernel<<<(20000 + 255) / 256, 256, 0, stream>>>(wcomp, ratt, relw);
    wth_kernel<<<(20800 + 255) / 256, 256, 0, stream>>>(Wkw, Wqw, Wvw, Wsw, Wth);
    proj_kernel<<<dim3((N_NODES + 63) / 64, 4), 512, 0, stream>>>(
        X, Wth, Wkb, Wqb, Wvb, Wsb, khp, q, vhp, out);

    hist_kernel<<<(N_EDGES + 255) / 256, 256, 0, stream>>>(dst, cnt);
    scanA_kernel<<<SCAN_NB, 1024, 0, stream>>>(cnt, partial, bsum);
    scanB_kernel<<<1, 1024, 0, stream>>>(partial, bsum, offs);
    scatter_kernel<<<(N_EDGES + 255) / 256, 256, 0, stream>>>(
        src, dst, ety, offs, cursor, psrc, pdst, pety);

    attp_kernel<<<(N_EDGES + 7) / 8, 256, 0, stream>>>(
        khp, q, relw, psrc, pdst, pety, attp);
    agg_kernel<<<AGG_NB, 256, 0, stream>>>(
        offs, psrc, attp, (const unsigned short*)vhp, alpha, out, bnpart);
    bnfin_kernel<<<25, 256, 0, stream>>>(bnpart, gamma, beta, bnsc, bnsh);
    apply_kernel<<<2048, 256, 0, stream>>>(out, bnsc, bnsh);
    rout_kernel<<<(20000 + 255) / 256, 256, 0, stream>>>(rfeat, Wrw, Wrb, out);
}

// Round 18
// 288.486 us; speedup vs baseline: 1.5018x; 1.1100x over previous
//
#include <hip/hip_runtime.h>
#include <hip/hip_bf16.h>
#include <math.h>

#define N_NODES 50000
#define N_EDGES 800000
#define BN_EPS  1e-5f
#define SCAN_NB 49     // ceil(50000/1024)
#define AGG_NB  2048   // agg grid blocks

typedef float floatx2 __attribute__((ext_vector_type(2)));
typedef _Float16 half2_t __attribute__((ext_vector_type(2)));

#if defined(__has_builtin) && __has_builtin(__builtin_amdgcn_fdot2)
#define FDOT2(a, b, c) __builtin_amdgcn_fdot2((a), (b), (c), false)
#else
#define FDOT2(a, b, c) ((c) + (float)(a).x * (float)(b).x + (float)(a).y * (float)(b).y)
#endif

union h2u { half2_t h; unsigned u; };

// ---- workspace layout (float-element offsets) ----
#define OFS_RELW   0                    // 200*128 padded relw
#define OFS_KH     25600                // 50000*32 uints (fp8 rows, 128B)
#define OFS_Q      1625600              // 50000*128 padded q
#define OFS_VH     8025600              // 50000*32 uints
#define OFS_ATTP   9625600
#define OFS_BNPART 10425600             // 200 * AGG_NB
#define OFS_BNSC   10835200
#define OFS_BNSH   10835328
#define OFS_CNT    10835456
#define OFS_PART   10885632
#define OFS_BSUM   10935808
#define OFS_OFFS   10935872
#define OFS_CURS   10986048
#define OFS_PSRC   11036224
#define OFS_PDST   11836224
#define OFS_PETY   12636224
#define OFS_WT     13436224             // 4*50*104 packed half2 W
#define WS_ELEMS   13457024

// rel_w[r][c] (padded to 128 cols, zero pad)
__global__ __launch_bounds__(256) void relw_kernel(
    const float* __restrict__ wcomp, const float* __restrict__ ratt,
    float* __restrict__ relw)
{
    int o = blockIdx.x * 256 + threadIdx.x;
    if (o >= 200 * 128) return;
    int r = o / 128, c = o % 128;
    float acc = 0.f;
    if (c < 100) {
        #pragma unroll 10
        for (int b = 0; b < 50; ++b) acc += wcomp[r * 50 + b] * ratt[b * 100 + c];
    }
    relw[o] = acc;
}

// pack W to d-pair-major half2: Wth[m][d2][c]
__global__ __launch_bounds__(256) void wth_kernel(
    const float* __restrict__ Wk, const float* __restrict__ Wq,
    const float* __restrict__ Wv, const float* __restrict__ Ws,
    unsigned* __restrict__ Wth)
{
    int o = blockIdx.x * 256 + threadIdx.x;
    if (o >= 4 * 50 * 104) return;
    int m = o / 5200, rem = o % 5200, d2 = rem / 104, c = rem % 104;
    const float* W = (m == 0) ? Wk : (m == 1) ? Wq : (m == 2) ? Wv : Ws;
    float a = (c < 100) ? W[c * 100 + 2 * d2]     : 0.f;
    float b = (c < 100) ? W[c * 100 + 2 * d2 + 1] : 0.f;
    h2u cv; cv.h = half2_t{(_Float16)a, (_Float16)b};
    Wth[o] = cv.u;
}

// fused projections (R17 half2+fdot2 structure). Outputs:
//  m=0 k -> fp8 rows of 32 words, words 25-31 zeroed
//  m=1 q -> fp32 rows of 128 floats, cols 100-127 zeroed
//  m=2 v -> fp8 rows, pad zeroed
//  m=3 s -> fp32 rows of 100 (d_out)
__global__ __launch_bounds__(512) void proj_kernel(
    const float* __restrict__ X, const unsigned* __restrict__ Wth,
    const float* __restrict__ bk, const float* __restrict__ bq,
    const float* __restrict__ bv, const float* __restrict__ bs,
    unsigned* __restrict__ khp, float* __restrict__ qo,
    unsigned* __restrict__ vhp, float* __restrict__ so)
{
    __shared__ unsigned Xth[50][68];    // 13.6 KB
    __shared__ unsigned Wlh[50][104];   // 20.8 KB
    const int tid = threadIdx.x;
    const int nb  = blockIdx.x * 64;
    const int m   = blockIdx.y;

    const float* bp = (m == 0) ? bk : (m == 1) ? bq : (m == 2) ? bv : bs;

    for (int idx = tid; idx < 1300; idx += 512) {
        int r = idx / 26, c4 = idx % 26;
        uint4 w = ((const uint4*)(Wth + m * 5200 + r * 104))[c4];
        *(uint4*)&Wlh[r][c4 * 4] = w;
    }
    for (int idx = tid; idx < 1600; idx += 512) {
        int n = idx / 25, d4 = idx % 25;
        int node = nb + n;
        float4 x = (node < N_NODES)
                   ? ((const float4*)(X + (size_t)node * 100))[d4]
                   : make_float4(0.f, 0.f, 0.f, 0.f);
        const int col = n ^ ((d4 & 7) << 2);
        h2u c0, c1;
        c0.h = half2_t{(_Float16)x.x, (_Float16)x.y};
        c1.h = half2_t{(_Float16)x.z, (_Float16)x.w};
        Xth[2 * d4][col]     = c0.u;
        Xth[2 * d4 + 1][col] = c1.u;
    }
    __syncthreads();

    const int nt  = tid & 15;
    const int ct  = tid >> 4;        // 0..31 (25 active compute, rest pad-write)
    const bool act = (ct < 25);
    const int cts  = act ? ct : 24;

    float acc[4][4];
    #pragma unroll
    for (int i = 0; i < 4; ++i)
        #pragma unroll
        for (int j = 0; j < 4; ++j) acc[i][j] = 0.f;

    #pragma unroll 5
    for (int d2 = 0; d2 < 50; ++d2) {
        const int key = ((d2 >> 1) & 7) << 2;
        const uint4 xv = *(const uint4*)&Xth[d2][(4 * nt) ^ key];
        const uint4 wv = *(const uint4*)&Wlh[d2][4 * cts];
        h2u x0, x1, x2, x3, w0, w1, w2, w3;
        x0.u = xv.x; x1.u = xv.y; x2.u = xv.z; x3.u = xv.w;
        w0.u = wv.x; w1.u = wv.y; w2.u = wv.z; w3.u = wv.w;
        acc[0][0] = FDOT2(x0.h, w0.h, acc[0][0]);
        acc[0][1] = FDOT2(x0.h, w1.h, acc[0][1]);
        acc[0][2] = FDOT2(x0.h, w2.h, acc[0][2]);
        acc[0][3] = FDOT2(x0.h, w3.h, acc[0][3]);
        acc[1][0] = FDOT2(x1.h, w0.h, acc[1][0]);
        acc[1][1] = FDOT2(x1.h, w1.h, acc[1][1]);
        acc[1][2] = FDOT2(x1.h, w2.h, acc[1][2]);
        acc[1][3] = FDOT2(x1.h, w3.h, acc[1][3]);
        acc[2][0] = FDOT2(x2.h, w0.h, acc[2][0]);
        acc[2][1] = FDOT2(x2.h, w1.h, acc[2][1]);
        acc[2][2] = FDOT2(x2.h, w2.h, acc[2][2]);
        acc[2][3] = FDOT2(x2.h, w3.h, acc[2][3]);
        acc[3][0] = FDOT2(x3.h, w0.h, acc[3][0]);
        acc[3][1] = FDOT2(x3.h, w1.h, acc[3][1]);
        acc[3][2] = FDOT2(x3.h, w2.h, acc[3][2]);
        acc[3][3] = FDOT2(x3.h, w3.h, acc[3][3]);
    }

    const float4 bb = act ? *(const float4*)(bp + ct * 4)
                          : make_float4(0.f, 0.f, 0.f, 0.f);
    if (m == 0 || m == 2) {
        unsigned* oph = (m == 0) ? khp : vhp;
        #pragma unroll
        for (int i = 0; i < 4; ++i) {
            const int node = nb + nt * 4 + i;
            if (node < N_NODES) {
                unsigned wdo = 0u;
                if (act) {
                    int wd = 0;
                    wd = __builtin_amdgcn_cvt_pk_fp8_f32(
                        acc[i][0] + bb.x, acc[i][1] + bb.y, wd, false);
                    wd = __builtin_amdgcn_cvt_pk_fp8_f32(
                        acc[i][2] + bb.z, acc[i][3] + bb.w, wd, true);
                    wdo = (unsigned)wd;
                }
                oph[(size_t)node * 32 + ct] = wdo;   // pad words -> 0
            }
        }
    } else if (m == 1) {
        #pragma unroll
        for (int i = 0; i < 4; ++i) {
            const int node = nb + nt * 4 + i;
            if (node < N_NODES) {
                float4 r = act ? make_float4(acc[i][0] + bb.x, acc[i][1] + bb.y,
                                             acc[i][2] + bb.z, acc[i][3] + bb.w)
                               : make_float4(0.f, 0.f, 0.f, 0.f);
                *(float4*)(qo + (size_t)node * 128 + ct * 4) = r;  // pad -> 0
            }
        }
    } else {
        if (act) {
            #pragma unroll
            for (int i = 0; i < 4; ++i) {
                const int node = nb + nt * 4 + i;
                if (node < N_NODES) {
                    float4 r = make_float4(acc[i][0] + bb.x, acc[i][1] + bb.y,
                                           acc[i][2] + bb.z, acc[i][3] + bb.w);
                    *(float4*)(so + (size_t)node * 100 + ct * 4) = r;
                }
            }
        }
    }
}

__global__ __launch_bounds__(256) void hist_kernel(
    const int* __restrict__ dst, int* __restrict__ cnt)
{
    int e = blockIdx.x * 256 + threadIdx.x;
    if (e < N_EDGES) atomicAdd(&cnt[dst[e]], 1);
}

__global__ __launch_bounds__(1024) void scanA_kernel(
    const int* __restrict__ cnt, int* __restrict__ partial, int* __restrict__ bsum)
{
    __shared__ int buf[1024];
    int tid = threadIdx.x;
    int i = blockIdx.x * 1024 + tid;
    int val = (i < N_NODES) ? cnt[i] : 0;
    buf[tid] = val;
    __syncthreads();
    for (int off = 1; off < 1024; off <<= 1) {
        int t = (tid >= off) ? buf[tid - off] : 0;
        __syncthreads();
        buf[tid] += t;
        __syncthreads();
    }
    int incl = buf[tid];
    if (i < N_NODES) partial[i] = incl - val;
    if (tid == 1023) bsum[blockIdx.x] = incl;
}

__global__ __launch_bounds__(1024) void scanB_kernel(
    const int* __restrict__ partial, const int* __restrict__ bsum,
    int* __restrict__ offs)
{
    __shared__ int bs[64];
    int tid = threadIdx.x;
    if (tid < SCAN_NB) bs[tid] = bsum[tid];
    __syncthreads();
    if (tid == 0) {
        int run = 0;
        for (int b = 0; b < SCAN_NB; ++b) { int t = bs[b]; bs[b] = run; run += t; }
    }
    __syncthreads();
    for (int i = tid; i < N_NODES; i += 1024) offs[i] = partial[i] + bs[i >> 10];
    if (tid == 0) offs[N_NODES] = N_EDGES;
}

// scatter sorted copies of src/dst/etype
__global__ __launch_bounds__(256) void scatter_kernel(
    const int* __restrict__ src, const int* __restrict__ dst,
    const int* __restrict__ ety, const int* __restrict__ offs,
    int* __restrict__ cursor, int* __restrict__ psrc,
    int* __restrict__ pdst, int* __restrict__ pety)
{
    int e = blockIdx.x * 256 + threadIdx.x;
    if (e >= N_EDGES) return;
    int d = dst[e];
    int p = atomicAdd(&cursor[d], 1);
    int pos = offs[d] + p;
    psrc[pos] = src[e];
    pdst[pos] = d;
    pety[pos] = ety[e];
}

// attention logits: 16 lanes/edge, lane handles quads {l, l+16} of padded
// 128-col rows; all lanes active, 4 edges/wave, 4-step reduce.
__global__ __launch_bounds__(256) void attp_kernel(
    const unsigned* __restrict__ khp, const float* __restrict__ q,
    const float* __restrict__ relw, const int* __restrict__ psrc,
    const int* __restrict__ pdst, const int* __restrict__ pety,
    float* __restrict__ attp)
{
    const int lane = threadIdx.x & 15;
    const int i = blockIdx.x * 16 + (threadIdx.x >> 4);
    if (i >= N_EDGES) return;
    const int s_ = psrc[i], d_ = pdst[i], t_ = pety[i];

    const unsigned* kr = khp + (size_t)s_ * 32;
    const float4*   qr = (const float4*)(q + (size_t)d_ * 128);
    const float4*   wr = (const float4*)(relw + t_ * 128);

    const unsigned kw0 = kr[lane];
    const unsigned kw1 = kr[lane + 16];
    const float4 qv0 = qr[lane];
    const float4 qv1 = qr[lane + 16];
    const float4 wv0 = wr[lane];
    const float4 wv1 = wr[lane + 16];

    const floatx2 ka = __builtin_amdgcn_cvt_pk_f32_fp8((int)kw0, false);
    const floatx2 kb = __builtin_amdgcn_cvt_pk_f32_fp8((int)kw0, true);
    const floatx2 kc = __builtin_amdgcn_cvt_pk_f32_fp8((int)kw1, false);
    const floatx2 kd = __builtin_amdgcn_cvt_pk_f32_fp8((int)kw1, true);

    float acc = ka[0] * wv0.x * qv0.x + ka[1] * wv0.y * qv0.y
              + kb[0] * wv0.z * qv0.z + kb[1] * wv0.w * qv0.w
              + kc[0] * wv1.x * qv1.x + kc[1] * wv1.y * qv1.y
              + kd[0] * wv1.z * qv1.z + kd[1] * wv1.w * qv1.w;

    #pragma unroll
    for (int off = 8; off > 0; off >>= 1) acc += __shfl_xor(acc, off, 16);
    if (lane == 0) attp[i] = acc;
}

// one wave per node: softmax + weighted-V aggregate (v fp8) + gated combine
// + BN partials
__global__ __launch_bounds__(256) void agg_kernel(
    const int* __restrict__ offs, const int* __restrict__ psrc,
    const float* __restrict__ attp, const unsigned short* __restrict__ vhp,
    const float* __restrict__ alpha, float* __restrict__ out,
    float* __restrict__ bnpart)
{
    __shared__ float ls[100], lq[100];
    const int tid = threadIdx.x;
    if (tid < 100) { ls[tid] = 0.f; lq[tid] = 0.f; }
    __syncthreads();
    const int lane = tid & 63;
    const int gwave = blockIdx.x * 4 + (tid >> 6);
    const int nwaves = AGG_NB * 4;
    const float a = 1.f / (1.f + __expf(-alpha[0]));
    const float b = 1.f - a;
    const int cl = lane;             // lane owns columns 2cl, 2cl+1
    const bool act = (cl < 50);
    float sx = 0.f, sy = 0.f, qx = 0.f, qy = 0.f;

    for (int n = gwave; n < N_NODES; n += nwaves) {
        const int beg = offs[n], end = offs[n + 1];
        float m = -INFINITY;
        for (int i = beg + lane; i < end; i += 64) m = fmaxf(m, attp[i]);
        #pragma unroll
        for (int off = 32; off > 0; off >>= 1) m = fmaxf(m, __shfl_xor(m, off, 64));
        float ax = 0.f, ay = 0.f, wsum = 0.f;
        int i = beg;
        for (; i + 4 <= end; i += 4) {
            const int s0 = psrc[i], s1 = psrc[i + 1], s2 = psrc[i + 2], s3 = psrc[i + 3];
            const float w0 = __expf(attp[i] - m),     w1 = __expf(attp[i + 1] - m);
            const float w2 = __expf(attp[i + 2] - m), w3 = __expf(attp[i + 3] - m);
            wsum += w0 + w1 + w2 + w3;
            if (act) {
                const unsigned short h0 = vhp[(size_t)s0 * 64 + cl];
                const unsigned short h1 = vhp[(size_t)s1 * 64 + cl];
                const unsigned short h2 = vhp[(size_t)s2 * 64 + cl];
                const unsigned short h3 = vhp[(size_t)s3 * 64 + cl];
                const floatx2 v0 = __builtin_amdgcn_cvt_pk_f32_fp8((int)h0, false);
                const floatx2 v1 = __builtin_amdgcn_cvt_pk_f32_fp8((int)h1, false);
                const floatx2 v2 = __builtin_amdgcn_cvt_pk_f32_fp8((int)h2, false);
                const floatx2 v3 = __builtin_amdgcn_cvt_pk_f32_fp8((int)h3, false);
                ax += w0 * v0[0] + w1 * v1[0] + w2 * v2[0] + w3 * v3[0];
                ay += w0 * v0[1] + w1 * v1[1] + w2 * v2[1] + w3 * v3[1];
            }
        }
        for (; i < end; ++i) {
            const int s0 = psrc[i];
            const float w0 = __expf(attp[i] - m);
            wsum += w0;
            if (act) {
                const unsigned short h0 = vhp[(size_t)s0 * 64 + cl];
                const floatx2 v0 = __builtin_amdgcn_cvt_pk_f32_fp8((int)h0, false);
                ax += w0 * v0[0];
                ay += w0 * v0[1];
            }
        }
        const float inv = (wsum > 0.f) ? 1.f / wsum : 0.f;
        if (act) {
            float2* po = (float2*)(out + (size_t)n * 100);
            float2 cur = po[cl];
            float v0 = a * cur.x + b * ax * inv;
            float v1 = a * cur.y + b * ay * inv;
            po[cl] = make_float2(v0, v1);
            sx += v0; qx += v0 * v0;
            sy += v1; qy += v1 * v1;
        }
    }
    if (act) {
        atomicAdd(&ls[2 * cl], sx);     atomicAdd(&ls[2 * cl + 1], sy);
        atomicAdd(&lq[2 * cl], qx);     atomicAdd(&lq[2 * cl + 1], qy);
    }
    __syncthreads();
    if (tid < 100) {
        bnpart[(size_t)tid * AGG_NB + blockIdx.x]         = ls[tid];
        bnpart[(size_t)(tid + 100) * AGG_NB + blockIdx.x] = lq[tid];
    }
}

__global__ __launch_bounds__(256) void bnfin_kernel(
    const float* __restrict__ bnpart,
    const float* __restrict__ gamma, const float* __restrict__ beta,
    float* __restrict__ bnsc, float* __restrict__ bnsh)
{
    const int c = blockIdx.x * 4 + (threadIdx.x >> 6);
    const int lane = threadIdx.x & 63;
    if (c >= 100) return;
    float s = 0.f, q = 0.f;
    for (int b2 = lane; b2 < AGG_NB; b2 += 64) {
        s += bnpart[(size_t)c * AGG_NB + b2];
        q += bnpart[(size_t)(c + 100) * AGG_NB + b2];
    }
    #pragma unroll
    for (int off = 32; off > 0; off >>= 1) {
        s += __shfl_xor(s, off, 64);
        q += __shfl_xor(q, off, 64);
    }
    if (lane == 0) {
        const float inv_n = 1.f / (float)N_NODES;
        float mean = s * inv_n;
        float var = q * inv_n - mean * mean;
        float sc = gamma[c] * rsqrtf(var + BN_EPS);
        bnsc[c] = sc;
        bnsh[c] = beta[c] - mean * sc;
    }
}

__global__ __launch_bounds__(256) void apply_kernel(
    float* __restrict__ out, const float* __restrict__ bnsc,
    const float* __restrict__ bnsh)
{
    const int total4 = N_NODES * 25;
    for (int idx = blockIdx.x * 256 + threadIdx.x; idx < total4; idx += gridDim.x * 256) {
        float4* p = ((float4*)out) + idx;
        const int c = (idx % 25) * 4;
        float4 t = *p;
        t.x = tanhf(t.x * bnsc[c]     + bnsh[c]);
        t.y = tanhf(t.y * bnsc[c + 1] + bnsh[c + 1]);
        t.z = tanhf(t.z * bnsc[c + 2] + bnsh[c + 2]);
        t.w = tanhf(t.w * bnsc[c + 3] + bnsh[c + 3]);
        *p = t;
    }
}

__global__ __launch_bounds__(256) void rout_kernel(
    const float* __restrict__ rf, const float* __restrict__ Wr,
    const float* __restrict__ br, float* __restrict__ out)
{
    int o = blockIdx.x * 256 + threadIdx.x;
    if (o >= 200 * 100) return;
    int r = o / 100, c = o % 100;
    float acc = br[c];
    #pragma unroll 10
    for (int d = 0; d < 100; ++d) acc += rf[r * 100 + d] * Wr[c * 100 + d];
    out[N_NODES * 100 + o] = acc;
}

extern "C" void kernel_launch(void* const* d_in, const int* in_sizes, int n_in,
                              void* d_out, int out_size, void* d_ws, size_t ws_size,
                              hipStream_t stream) {
    const float* X     = (const float*)d_in[0];
    const float* rfeat = (const float*)d_in[1];
    const int*   src   = (const int*)d_in[2];
    const int*   dst   = (const int*)d_in[3];
    const int*   ety   = (const int*)d_in[4];
    const float* Wsw   = (const float*)d_in[6];
    const float* Wsb   = (const float*)d_in[7];
    const float* Wkw   = (const float*)d_in[8];
    const float* Wkb   = (const float*)d_in[9];
    const float* Wqw   = (const float*)d_in[10];
    const float* Wqb   = (const float*)d_in[11];
    const float* Wvw   = (const float*)d_in[12];
    const float* Wvb   = (const float*)d_in[13];
    const float* Wrw   = (const float*)d_in[14];
    const float* Wrb   = (const float*)d_in[15];
    const float* ratt  = (const float*)d_in[16];
    const float* wcomp = (const float*)d_in[17];
    const float* alpha = (const float*)d_in[18];
    const float* gamma = (const float*)d_in[20];
    const float* beta  = (const float*)d_in[21];

    float* out = (float*)d_out;
    float* ws  = (float*)d_ws;
    if (ws_size < (size_t)WS_ELEMS * sizeof(float)) return;

    float* relw          = ws + OFS_RELW;
    unsigned* khp        = (unsigned*)(ws + OFS_KH);
    float* q             = ws + OFS_Q;
    unsigned* vhp        = (unsigned*)(ws + OFS_VH);
    float* attp          = ws + OFS_ATTP;
    float* bnpart        = ws + OFS_BNPART;
    float* bnsc          = ws + OFS_BNSC;
    float* bnsh          = ws + OFS_BNSH;
    unsigned* Wth        = (unsigned*)(ws + OFS_WT);
    int* cnt             = (int*)(ws + OFS_CNT);
    int* partial         = (int*)(ws + OFS_PART);
    int* bsum            = (int*)(ws + OFS_BSUM);
    int* offs            = (int*)(ws + OFS_OFFS);
    int* cursor          = (int*)(ws + OFS_CURS);
    int* psrc            = (int*)(ws + OFS_PSRC);
    int* pdst            = (int*)(ws + OFS_PDST);
    int* pety            = (int*)(ws + OFS_PETY);

    hipMemsetAsync(cnt, 0, 50000 * sizeof(int), stream);
    hipMemsetAsync(cursor, 0, 50000 * sizeof(int), stream);

    relw_kernel<<<(200 * 128 + 255) / 256, 256, 0, stream>>>(wcomp, ratt, relw);
    wth_kernel<<<(20800 + 255) / 256, 256, 0, stream>>>(Wkw, Wqw, Wvw, Wsw, Wth);
    proj_kernel<<<dim3((N_NODES + 63) / 64, 4), 512, 0, stream>>>(
        X, Wth, Wkb, Wqb, Wvb, Wsb, khp, q, vhp, out);

    hist_kernel<<<(N_EDGES + 255) / 256, 256, 0, stream>>>(dst, cnt);
    scanA_kernel<<<SCAN_NB, 1024, 0, stream>>>(cnt, partial, bsum);
    scanB_kernel<<<1, 1024, 0, stream>>>(partial, bsum, offs);
    scatter_kernel<<<(N_EDGES + 255) / 256, 256, 0, stream>>>(
        src, dst, ety, offs, cursor, psrc, pdst, pety);

    attp_kernel<<<(N_EDGES + 15) / 16, 256, 0, stream>>>(
        khp, q, relw, psrc, pdst, pety, attp);
    agg_kernel<<<AGG_NB, 256, 0, stream>>>(
        offs, psrc, attp, (const unsigned short*)vhp, alpha, out, bnpart);
    bnfin_kernel<<<25, 256, 0, stream>>>(bnpart, gamma, beta, bnsc, bnsh);
    apply_kernel<<<2048, 256, 0, stream>>>(out, bnsc, bnsh);
    rout_kernel<<<(20000 + 255) / 256, 256, 0, stream>>>(rfeat, Wrw, Wrb, out);
}

// Round 19
// 287.659 us; speedup vs baseline: 1.5061x; 1.0029x over previous
//
#include <hip/hip_runtime.h>
#include <hip/hip_bf16.h>
#include <math.h>

#define N_NODES 50000
#define N_EDGES 800000
#define BN_EPS  1e-5f
#define SCAN_NB 49     // ceil(50000/1024)
#define AGG_NB  2048   // agg grid blocks

typedef float floatx2 __attribute__((ext_vector_type(2)));
typedef _Float16 half2_t __attribute__((ext_vector_type(2)));

#if defined(__has_builtin) && __has_builtin(__builtin_amdgcn_fdot2)
#define FDOT2(a, b, c) __builtin_amdgcn_fdot2((a), (b), (c), false)
#else
#define FDOT2(a, b, c) ((c) + (float)(a).x * (float)(b).x + (float)(a).y * (float)(b).y)
#endif

union h2u { half2_t h; unsigned u; };

// ---- workspace layout (float-element offsets) ----
#define OFS_RELW   0                    // 200*128 padded relw
#define OFS_KH     25600                // 50000*32 uints (fp8 rows, 128B)
#define OFS_Q      1625600              // 50000*128 padded q
#define OFS_VH     8025600              // 50000*32 uints
#define OFS_ATTP   9625600
#define OFS_BNPART 10425600             // 200 * AGG_NB
#define OFS_BNSC   10835200
#define OFS_BNSH   10835328
#define OFS_CNT    10835456
#define OFS_PART   10885632
#define OFS_BSUM   10935808
#define OFS_OFFS   10935872
#define OFS_CURS   10986048
#define OFS_PEDGE  11036224             // packed src|ety<<17, dst-sorted
#define OFS_PDST   11836224
#define OFS_WT     12636224             // 4*50*104 packed half2 W
#define WS_ELEMS   12657024

// rel_w[r][c] (padded to 128 cols, zero pad)
__global__ __launch_bounds__(256) void relw_kernel(
    const float* __restrict__ wcomp, const float* __restrict__ ratt,
    float* __restrict__ relw)
{
    int o = blockIdx.x * 256 + threadIdx.x;
    if (o >= 200 * 128) return;
    int r = o / 128, c = o % 128;
    float acc = 0.f;
    if (c < 100) {
        #pragma unroll 10
        for (int b = 0; b < 50; ++b) acc += wcomp[r * 50 + b] * ratt[b * 100 + c];
    }
    relw[o] = acc;
}

// pack W to d-pair-major half2: Wth[m][d2][c]
__global__ __launch_bounds__(256) void wth_kernel(
    const float* __restrict__ Wk, const float* __restrict__ Wq,
    const float* __restrict__ Wv, const float* __restrict__ Ws,
    unsigned* __restrict__ Wth)
{
    int o = blockIdx.x * 256 + threadIdx.x;
    if (o >= 4 * 50 * 104) return;
    int m = o / 5200, rem = o % 5200, d2 = rem / 104, c = rem % 104;
    const float* W = (m == 0) ? Wk : (m == 1) ? Wq : (m == 2) ? Wv : Ws;
    float a = (c < 100) ? W[c * 100 + 2 * d2]     : 0.f;
    float b = (c < 100) ? W[c * 100 + 2 * d2 + 1] : 0.f;
    h2u cv; cv.h = half2_t{(_Float16)a, (_Float16)b};
    Wth[o] = cv.u;
}

// fused projections (half2 + fdot2). Outputs: k,v fp8 (32-word rows, pad 0);
// q fp32 128-col rows (pad 0); s fp32 100-col rows.
__global__ __launch_bounds__(512) void proj_kernel(
    const float* __restrict__ X, const unsigned* __restrict__ Wth,
    const float* __restrict__ bk, const float* __restrict__ bq,
    const float* __restrict__ bv, const float* __restrict__ bs,
    unsigned* __restrict__ khp, float* __restrict__ qo,
    unsigned* __restrict__ vhp, float* __restrict__ so)
{
    __shared__ unsigned Xth[50][68];    // 13.6 KB
    __shared__ unsigned Wlh[50][104];   // 20.8 KB
    const int tid = threadIdx.x;
    const int nb  = blockIdx.x * 64;
    const int m   = blockIdx.y;

    const float* bp = (m == 0) ? bk : (m == 1) ? bq : (m == 2) ? bv : bs;

    for (int idx = tid; idx < 1300; idx += 512) {
        int r = idx / 26, c4 = idx % 26;
        uint4 w = ((const uint4*)(Wth + m * 5200 + r * 104))[c4];
        *(uint4*)&Wlh[r][c4 * 4] = w;
    }
    for (int idx = tid; idx < 1600; idx += 512) {
        int n = idx / 25, d4 = idx % 25;
        int node = nb + n;
        float4 x = (node < N_NODES)
                   ? ((const float4*)(X + (size_t)node * 100))[d4]
                   : make_float4(0.f, 0.f, 0.f, 0.f);
        const int col = n ^ ((d4 & 7) << 2);
        h2u c0, c1;
        c0.h = half2_t{(_Float16)x.x, (_Float16)x.y};
        c1.h = half2_t{(_Float16)x.z, (_Float16)x.w};
        Xth[2 * d4][col]     = c0.u;
        Xth[2 * d4 + 1][col] = c1.u;
    }
    __syncthreads();

    const int nt  = tid & 15;
    const int ct  = tid >> 4;        // 0..31 (25 active compute, rest pad-write)
    const bool act = (ct < 25);
    const int cts  = act ? ct : 24;

    float acc[4][4];
    #pragma unroll
    for (int i = 0; i < 4; ++i)
        #pragma unroll
        for (int j = 0; j < 4; ++j) acc[i][j] = 0.f;

    #pragma unroll 5
    for (int d2 = 0; d2 < 50; ++d2) {
        const int key = ((d2 >> 1) & 7) << 2;
        const uint4 xv = *(const uint4*)&Xth[d2][(4 * nt) ^ key];
        const uint4 wv = *(const uint4*)&Wlh[d2][4 * cts];
        h2u x0, x1, x2, x3, w0, w1, w2, w3;
        x0.u = xv.x; x1.u = xv.y; x2.u = xv.z; x3.u = xv.w;
        w0.u = wv.x; w1.u = wv.y; w2.u = wv.z; w3.u = wv.w;
        acc[0][0] = FDOT2(x0.h, w0.h, acc[0][0]);
        acc[0][1] = FDOT2(x0.h, w1.h, acc[0][1]);
        acc[0][2] = FDOT2(x0.h, w2.h, acc[0][2]);
        acc[0][3] = FDOT2(x0.h, w3.h, acc[0][3]);
        acc[1][0] = FDOT2(x1.h, w0.h, acc[1][0]);
        acc[1][1] = FDOT2(x1.h, w1.h, acc[1][1]);
        acc[1][2] = FDOT2(x1.h, w2.h, acc[1][2]);
        acc[1][3] = FDOT2(x1.h, w3.h, acc[1][3]);
        acc[2][0] = FDOT2(x2.h, w0.h, acc[2][0]);
        acc[2][1] = FDOT2(x2.h, w1.h, acc[2][1]);
        acc[2][2] = FDOT2(x2.h, w2.h, acc[2][2]);
        acc[2][3] = FDOT2(x2.h, w3.h, acc[2][3]);
        acc[3][0] = FDOT2(x3.h, w0.h, acc[3][0]);
        acc[3][1] = FDOT2(x3.h, w1.h, acc[3][1]);
        acc[3][2] = FDOT2(x3.h, w2.h, acc[3][2]);
        acc[3][3] = FDOT2(x3.h, w3.h, acc[3][3]);
    }

    const float4 bb = act ? *(const float4*)(bp + ct * 4)
                          : make_float4(0.f, 0.f, 0.f, 0.f);
    if (m == 0 || m == 2) {
        unsigned* oph = (m == 0) ? khp : vhp;
        #pragma unroll
        for (int i = 0; i < 4; ++i) {
            const int node = nb + nt * 4 + i;
            if (node < N_NODES) {
                unsigned wdo = 0u;
                if (act) {
                    int wd = 0;
                    wd = __builtin_amdgcn_cvt_pk_fp8_f32(
                        acc[i][0] + bb.x, acc[i][1] + bb.y, wd, false);
                    wd = __builtin_amdgcn_cvt_pk_fp8_f32(
                        acc[i][2] + bb.z, acc[i][3] + bb.w, wd, true);
                    wdo = (unsigned)wd;
                }
                oph[(size_t)node * 32 + ct] = wdo;
            }
        }
    } else if (m == 1) {
        #pragma unroll
        for (int i = 0; i < 4; ++i) {
            const int node = nb + nt * 4 + i;
            if (node < N_NODES) {
                float4 r = act ? make_float4(acc[i][0] + bb.x, acc[i][1] + bb.y,
                                             acc[i][2] + bb.z, acc[i][3] + bb.w)
                               : make_float4(0.f, 0.f, 0.f, 0.f);
                *(float4*)(qo + (size_t)node * 128 + ct * 4) = r;
            }
        }
    } else {
        if (act) {
            #pragma unroll
            for (int i = 0; i < 4; ++i) {
                const int node = nb + nt * 4 + i;
                if (node < N_NODES) {
                    float4 r = make_float4(acc[i][0] + bb.x, acc[i][1] + bb.y,
                                           acc[i][2] + bb.z, acc[i][3] + bb.w);
                    *(float4*)(so + (size_t)node * 100 + ct * 4) = r;
                }
            }
        }
    }
}

__global__ __launch_bounds__(256) void hist_kernel(
    const int* __restrict__ dst, int* __restrict__ cnt)
{
    int e = blockIdx.x * 256 + threadIdx.x;
    if (e < N_EDGES) atomicAdd(&cnt[dst[e]], 1);
}

__global__ __launch_bounds__(1024) void scanA_kernel(
    const int* __restrict__ cnt, int* __restrict__ partial, int* __restrict__ bsum)
{
    __shared__ int buf[1024];
    int tid = threadIdx.x;
    int i = blockIdx.x * 1024 + tid;
    int val = (i < N_NODES) ? cnt[i] : 0;
    buf[tid] = val;
    __syncthreads();
    for (int off = 1; off < 1024; off <<= 1) {
        int t = (tid >= off) ? buf[tid - off] : 0;
        __syncthreads();
        buf[tid] += t;
        __syncthreads();
    }
    int incl = buf[tid];
    if (i < N_NODES) partial[i] = incl - val;
    if (tid == 1023) bsum[blockIdx.x] = incl;
}

__global__ __launch_bounds__(1024) void scanB_kernel(
    const int* __restrict__ partial, const int* __restrict__ bsum,
    int* __restrict__ offs)
{
    __shared__ int bs[64];
    int tid = threadIdx.x;
    if (tid < SCAN_NB) bs[tid] = bsum[tid];
    __syncthreads();
    if (tid == 0) {
        int run = 0;
        for (int b = 0; b < SCAN_NB; ++b) { int t = bs[b]; bs[b] = run; run += t; }
    }
    __syncthreads();
    for (int i = tid; i < N_NODES; i += 1024) offs[i] = partial[i] + bs[i >> 10];
    if (tid == 0) offs[N_NODES] = N_EDGES;
}

// scatter ONE packed word per edge: src | (ety << 17)
__global__ __launch_bounds__(256) void scatter_kernel(
    const int* __restrict__ src, const int* __restrict__ dst,
    const int* __restrict__ ety, const int* __restrict__ offs,
    int* __restrict__ cursor, unsigned* __restrict__ pedge)
{
    int e = blockIdx.x * 256 + threadIdx.x;
    if (e >= N_EDGES) return;
    int d = dst[e];
    int p = atomicAdd(&cursor[d], 1);
    pedge[offs[d] + p] = (unsigned)src[e] | ((unsigned)ety[e] << 17);
}

// sequential pdst fill: wave per node writes n over [offs[n], offs[n+1])
__global__ __launch_bounds__(256) void pdstfill_kernel(
    const int* __restrict__ offs, int* __restrict__ pdst)
{
    const int lane = threadIdx.x & 63;
    const int gwave = blockIdx.x * 4 + (threadIdx.x >> 6);
    const int nwaves = gridDim.x * 4;
    for (int n = gwave; n < N_NODES; n += nwaves) {
        const int beg = offs[n], end = offs[n + 1];
        for (int i = beg + lane; i < end; i += 64) pdst[i] = n;
    }
}

// attention logits: 16 lanes/edge on padded-128 rows; 4 edges/wave.
__global__ __launch_bounds__(256) void attp_kernel(
    const unsigned* __restrict__ khp, const float* __restrict__ q,
    const float* __restrict__ relw, const unsigned* __restrict__ pedge,
    const int* __restrict__ pdst, float* __restrict__ attp)
{
    const int lane = threadIdx.x & 15;
    const int i = blockIdx.x * 16 + (threadIdx.x >> 4);
    if (i >= N_EDGES) return;
    const unsigned pw = pedge[i];
    const int s_ = (int)(pw & 0x1FFFFu);
    const int t_ = (int)(pw >> 17);
    const int d_ = pdst[i];

    const unsigned* kr = khp + (size_t)s_ * 32;
    const float4*   qr = (const float4*)(q + (size_t)d_ * 128);
    const float4*   wr = (const float4*)(relw + t_ * 128);

    const unsigned kw0 = kr[lane];
    const unsigned kw1 = kr[lane + 16];
    const float4 qv0 = qr[lane];
    const float4 qv1 = qr[lane + 16];
    const float4 wv0 = wr[lane];
    const float4 wv1 = wr[lane + 16];

    const floatx2 ka = __builtin_amdgcn_cvt_pk_f32_fp8((int)kw0, false);
    const floatx2 kb = __builtin_amdgcn_cvt_pk_f32_fp8((int)kw0, true);
    const floatx2 kc = __builtin_amdgcn_cvt_pk_f32_fp8((int)kw1, false);
    const floatx2 kd = __builtin_amdgcn_cvt_pk_f32_fp8((int)kw1, true);

    float acc = ka[0] * wv0.x * qv0.x + ka[1] * wv0.y * qv0.y
              + kb[0] * wv0.z * qv0.z + kb[1] * wv0.w * qv0.w
              + kc[0] * wv1.x * qv1.x + kc[1] * wv1.y * qv1.y
              + kd[0] * wv1.z * qv1.z + kd[1] * wv1.w * qv1.w;

    #pragma unroll
    for (int off = 8; off > 0; off >>= 1) acc += __shfl_xor(acc, off, 16);
    if (lane == 0) attp[i] = acc;
}

// one wave per node: softmax + weighted-V aggregate (v fp8) + gated combine
// + BN partials
__global__ __launch_bounds__(256) void agg_kernel(
    const int* __restrict__ offs, const unsigned* __restrict__ pedge,
    const float* __restrict__ attp, const unsigned short* __restrict__ vhp,
    const float* __restrict__ alpha, float* __restrict__ out,
    float* __restrict__ bnpart)
{
    __shared__ float ls[100], lq[100];
    const int tid = threadIdx.x;
    if (tid < 100) { ls[tid] = 0.f; lq[tid] = 0.f; }
    __syncthreads();
    const int lane = tid & 63;
    const int gwave = blockIdx.x * 4 + (tid >> 6);
    const int nwaves = AGG_NB * 4;
    const float a = 1.f / (1.f + __expf(-alpha[0]));
    const float b = 1.f - a;
    const int cl = lane;             // lane owns columns 2cl, 2cl+1
    const bool act = (cl < 50);
    float sx = 0.f, sy = 0.f, qx = 0.f, qy = 0.f;

    for (int n = gwave; n < N_NODES; n += nwaves) {
        const int beg = offs[n], end = offs[n + 1];
        float m = -INFINITY;
        for (int i = beg + lane; i < end; i += 64) m = fmaxf(m, attp[i]);
        #pragma unroll
        for (int off = 32; off > 0; off >>= 1) m = fmaxf(m, __shfl_xor(m, off, 64));
        float ax = 0.f, ay = 0.f, wsum = 0.f;
        int i = beg;
        for (; i + 4 <= end; i += 4) {
            const int s0 = (int)(pedge[i]     & 0x1FFFFu);
            const int s1 = (int)(pedge[i + 1] & 0x1FFFFu);
            const int s2 = (int)(pedge[i + 2] & 0x1FFFFu);
            const int s3 = (int)(pedge[i + 3] & 0x1FFFFu);
            const float w0 = __expf(attp[i] - m),     w1 = __expf(attp[i + 1] - m);
            const float w2 = __expf(attp[i + 2] - m), w3 = __expf(attp[i + 3] - m);
            wsum += w0 + w1 + w2 + w3;
            if (act) {
                const unsigned short h0 = vhp[(size_t)s0 * 64 + cl];
                const unsigned short h1 = vhp[(size_t)s1 * 64 + cl];
                const unsigned short h2 = vhp[(size_t)s2 * 64 + cl];
                const unsigned short h3 = vhp[(size_t)s3 * 64 + cl];
                const floatx2 v0 = __builtin_amdgcn_cvt_pk_f32_fp8((int)h0, false);
                const floatx2 v1 = __builtin_amdgcn_cvt_pk_f32_fp8((int)h1, false);
                const floatx2 v2 = __builtin_amdgcn_cvt_pk_f32_fp8((int)h2, false);
                const floatx2 v3 = __builtin_amdgcn_cvt_pk_f32_fp8((int)h3, false);
                ax += w0 * v0[0] + w1 * v1[0] + w2 * v2[0] + w3 * v3[0];
                ay += w0 * v0[1] + w1 * v1[1] + w2 * v2[1] + w3 * v3[1];
            }
        }
        for (; i < end; ++i) {
            const int s0 = (int)(pedge[i] & 0x1FFFFu);
            const float w0 = __expf(attp[i] - m);
            wsum += w0;
            if (act) {
                const unsigned short h0 = vhp[(size_t)s0 * 64 + cl];
                const floatx2 v0 = __builtin_amdgcn_cvt_pk_f32_fp8((int)h0, false);
                ax += w0 * v0[0];
                ay += w0 * v0[1];
            }
        }
        const float inv = (wsum > 0.f) ? 1.f / wsum : 0.f;
        if (act) {
            float2* po = (float2*)(out + (size_t)n * 100);
            float2 cur = po[cl];
            float v0 = a * cur.x + b * ax * inv;
            float v1 = a * cur.y + b * ay * inv;
            po[cl] = make_float2(v0, v1);
            sx += v0; qx += v0 * v0;
            sy += v1; qy += v1 * v1;
        }
    }
    if (act) {
        atomicAdd(&ls[2 * cl], sx);     atomicAdd(&ls[2 * cl + 1], sy);
        atomicAdd(&lq[2 * cl], qx);     atomicAdd(&lq[2 * cl + 1], qy);
    }
    __syncthreads();
    if (tid < 100) {
        bnpart[(size_t)tid * AGG_NB + blockIdx.x]         = ls[tid];
        bnpart[(size_t)(tid + 100) * AGG_NB + blockIdx.x] = lq[tid];
    }
}

__global__ __launch_bounds__(256) void bnfin_kernel(
    const float* __restrict__ bnpart,
    const float* __restrict__ gamma, const float* __restrict__ beta,
    float* __restrict__ bnsc, float* __restrict__ bnsh)
{
    const int c = blockIdx.x * 4 + (threadIdx.x >> 6);
    const int lane = threadIdx.x & 63;
    if (c >= 100) return;
    float s = 0.f, q = 0.f;
    for (int b2 = lane; b2 < AGG_NB; b2 += 64) {
        s += bnpart[(size_t)c * AGG_NB + b2];
        q += bnpart[(size_t)(c + 100) * AGG_NB + b2];
    }
    #pragma unroll
    for (int off = 32; off > 0; off >>= 1) {
        s += __shfl_xor(s, off, 64);
        q += __shfl_xor(q, off, 64);
    }
    if (lane == 0) {
        const float inv_n = 1.f / (float)N_NODES;
        float mean = s * inv_n;
        float var = q * inv_n - mean * mean;
        float sc = gamma[c] * rsqrtf(var + BN_EPS);
        bnsc[c] = sc;
        bnsh[c] = beta[c] - mean * sc;
    }
}

__global__ __launch_bounds__(256) void apply_kernel(
    float* __restrict__ out, const float* __restrict__ bnsc,
    const float* __restrict__ bnsh)
{
    const int total4 = N_NODES * 25;
    for (int idx = blockIdx.x * 256 + threadIdx.x; idx < total4; idx += gridDim.x * 256) {
        float4* p = ((float4*)out) + idx;
        const int c = (idx % 25) * 4;
        float4 t = *p;
        t.x = tanhf(t.x * bnsc[c]     + bnsh[c]);
        t.y = tanhf(t.y * bnsc[c + 1] + bnsh[c + 1]);
        t.z = tanhf(t.z * bnsc[c + 2] + bnsh[c + 2]);
        t.w = tanhf(t.w * bnsc[c + 3] + bnsh[c + 3]);
        *p = t;
    }
}

__global__ __launch_bounds__(256) void rout_kernel(
    const float* __restrict__ rf, const float* __restrict__ Wr,
    const float* __restrict__ br, float* __restrict__ out)
{
    int o = blockIdx.x * 256 + threadIdx.x;
    if (o >= 200 * 100) return;
    int r = o / 100, c = o % 100;
    float acc = br[c];
    #pragma unroll 10
    for (int d = 0; d < 100; ++d) acc += rf[r * 100 + d] * Wr[c * 100 + d];
    out[N_NODES * 100 + o] = acc;
}

extern "C" void kernel_launch(void* const* d_in, const int* in_sizes, int n_in,
                              void* d_out, int out_size, void* d_ws, size_t ws_size,
                              hipStream_t stream) {
    const float* X     = (const float*)d_in[0];
    const float* rfeat = (const float*)d_in[1];
    const int*   src   = (const int*)d_in[2];
    const int*   dst   = (const int*)d_in[3];
    const int*   ety   = (const int*)d_in[4];
    const float* Wsw   = (const float*)d_in[6];
    const float* Wsb   = (const float*)d_in[7];
    const float* Wkw   = (const float*)d_in[8];
    const float* Wkb   = (const float*)d_in[9];
    const float* Wqw   = (const float*)d_in[10];
    const float* Wqb   = (const float*)d_in[11];
    const float* Wvw   = (const float*)d_in[12];
    const float* Wvb   = (const float*)d_in[13];
    const float* Wrw   = (const float*)d_in[14];
    const float* Wrb   = (const float*)d_in[15];
    const float* ratt  = (const float*)d_in[16];
    const float* wcomp = (const float*)d_in[17];
    const float* alpha = (const float*)d_in[18];
    const float* gamma = (const float*)d_in[20];
    const float* beta  = (const float*)d_in[21];

    float* out = (float*)d_out;
    float* ws  = (float*)d_ws;
    if (ws_size < (size_t)WS_ELEMS * sizeof(float)) return;

    float* relw          = ws + OFS_RELW;
    unsigned* khp        = (unsigned*)(ws + OFS_KH);
    float* q             = ws + OFS_Q;
    unsigned* vhp        = (unsigned*)(ws + OFS_VH);
    float* attp          = ws + OFS_ATTP;
    float* bnpart        = ws + OFS_BNPART;
    float* bnsc          = ws + OFS_BNSC;
    float* bnsh          = ws + OFS_BNSH;
    unsigned* Wth        = (unsigned*)(ws + OFS_WT);
    int* cnt             = (int*)(ws + OFS_CNT);
    int* partial         = (int*)(ws + OFS_PART);
    int* bsum            = (int*)(ws + OFS_BSUM);
    int* offs            = (int*)(ws + OFS_OFFS);
    int* cursor          = (int*)(ws + OFS_CURS);
    unsigned* pedge      = (unsigned*)(ws + OFS_PEDGE);
    int* pdst            = (int*)(ws + OFS_PDST);

    hipMemsetAsync(cnt, 0, 50000 * sizeof(int), stream);
    hipMemsetAsync(cursor, 0, 50000 * sizeof(int), stream);

    relw_kernel<<<(200 * 128 + 255) / 256, 256, 0, stream>>>(wcomp, ratt, relw);
    wth_kernel<<<(20800 + 255) / 256, 256, 0, stream>>>(Wkw, Wqw, Wvw, Wsw, Wth);
    proj_kernel<<<dim3((N_NODES + 63) / 64, 4), 512, 0, stream>>>(
        X, Wth, Wkb, Wqb, Wvb, Wsb, khp, q, vhp, out);

    hist_kernel<<<(N_EDGES + 255) / 256, 256, 0, stream>>>(dst, cnt);
    scanA_kernel<<<SCAN_NB, 1024, 0, stream>>>(cnt, partial, bsum);
    scanB_kernel<<<1, 1024, 0, stream>>>(partial, bsum, offs);
    scatter_kernel<<<(N_EDGES + 255) / 256, 256, 0, stream>>>(
        src, dst, ety, offs, cursor, pedge);
    pdstfill_kernel<<<2048, 256, 0, stream>>>(offs, pdst);

    attp_kernel<<<(N_EDGES + 15) / 16, 256, 0, stream>>>(
        khp, q, relw, pedge, pdst, attp);
    agg_kernel<<<AGG_NB, 256, 0, stream>>>(
        offs, pedge, attp, (const unsigned short*)vhp, alpha, out, bnpart);
    bnfin_kernel<<<25, 256, 0, stream>>>(bnpart, gamma, beta, bnsc, bnsh);
    apply_kernel<<<2048, 256, 0, stream>>>(out, bnsc, bnsh);
    rout_kernel<<<(20000 + 255) / 256, 256, 0, stream>>>(rfeat, Wrw, Wrb, out);
}